// Round 1
// baseline (2706.046 us; speedup 1.0000x reference)
//
#include <hip/hip_runtime.h>

// ViTMoEAttention: B=32,S=257,D=1024,H=16,HD=64,E=8,R=16,K=2
// fp32 everywhere (no fp32 MFMA on CDNA4; bf16 rounding too lossy for the
// 3.07e-3 absmax threshold at this stage). Vector-ALU tiled GEMMs.
//
// Workspace layout (floats): qbuf[M*D], vbuf[M*D], xa_q/k/v/o[M*32]
//   -> needs ~71.6 MB. k-projection buffer lives in d_out (dead before the
//      final GEMM overwrites d_out).

#define BB 32
#define SS 257
#define DD 1024
#define HH 16
#define HDIM 64
#define EE 8
#define RR 16
#define KEXP 2
#define MTOT (BB * SS) // 8224

static __device__ __forceinline__ float4 ld4(const float* p) {
    return *(const float4*)p;
}

// ---------------------------------------------------------------------------
// xa[b][s][ke*16+r] = gates[b][ke] * sum_d X[b][s][d] * A[idx[b][ke]][r][d]
// grid: (ceil(S/16)=17, B*KEXP), block 256 = (r=16) x (s=16)
// ---------------------------------------------------------------------------
__global__ __launch_bounds__(256) void xa_kernel(
    const float* __restrict__ X, const float* __restrict__ A,
    const int* __restrict__ idx, const float* __restrict__ gates,
    float* __restrict__ xa)
{
    int bk2 = blockIdx.y;
    int b = bk2 >> 1, ke = bk2 & 1;
    int r = threadIdx.x & 15;
    int si = threadIdx.x >> 4;
    int s = blockIdx.x * 16 + si;
    if (s >= SS) return;
    int e = idx[b * KEXP + ke];
    float g = gates[b * KEXP + ke];
    const float* xrow = X + (size_t)(b * SS + s) * DD;
    const float* arow = A + (size_t)(e * RR + r) * DD;
    float acc = 0.f;
#pragma unroll 8
    for (int d = 0; d < DD; d += 4) {
        float4 xv = ld4(xrow + d);
        float4 av = ld4(arow + d);
        acc = fmaf(xv.x, av.x, acc);
        acc = fmaf(xv.y, av.y, acc);
        acc = fmaf(xv.z, av.z, acc);
        acc = fmaf(xv.w, av.w, acc);
    }
    xa[(b * SS + s) * (KEXP * RR) + ke * RR + r] = g * acc;
}

// ---------------------------------------------------------------------------
// C[m][n] = alpha * ( sum_d X[m][d]*W[n][d] + expert + bias[n] )
// expert: 32-deep K-tail using xa (gate-scaled) and gathered B_all[idx[b]].
// Tiles: BM=BN=128, BK=16, 256 threads, 8x8 per thread (4x4 quadrants).
// grid: (8 ntiles, 65 mtiles)
// ---------------------------------------------------------------------------
#define COMPUTE_TILE()                                                         \
    do {                                                                       \
        _Pragma("unroll") for (int kk = 0; kk < 16; ++kk) {                    \
            float4 a0 = ld4(&As[kk][ty4]);                                     \
            float4 a1 = ld4(&As[kk][ty4 + 64]);                                \
            float4 b0 = ld4(&Bs[kk][tx4]);                                     \
            float4 b1 = ld4(&Bs[kk][tx4 + 64]);                                \
            float am[2][4] = {{a0.x, a0.y, a0.z, a0.w},                        \
                              {a1.x, a1.y, a1.z, a1.w}};                       \
            float bn[2][4] = {{b0.x, b0.y, b0.z, b0.w},                        \
                              {b1.x, b1.y, b1.z, b1.w}};                       \
            _Pragma("unroll") for (int qm = 0; qm < 2; ++qm)                   \
            _Pragma("unroll") for (int qn = 0; qn < 2; ++qn)                   \
            _Pragma("unroll") for (int i = 0; i < 4; ++i)                      \
            _Pragma("unroll") for (int j = 0; j < 4; ++j)                      \
                acc[qm][qn][i][j] =                                            \
                    fmaf(am[qm][i], bn[qn][j], acc[qm][qn][i][j]);             \
        }                                                                      \
    } while (0)

__global__ __launch_bounds__(256) void gemm_lora(
    const float* __restrict__ X, const float* __restrict__ W,
    const float* __restrict__ bias, const float* __restrict__ xa,
    const float* __restrict__ Ball, const int* __restrict__ idx,
    float* __restrict__ C, float alpha)
{
    __shared__ float As[16][132]; // [k][m], pad to 132 (2-way max on stores)
    __shared__ float Bs[16][132]; // [k][n]
    const int tid = threadIdx.x;
    const int tx4 = (tid & 15) * 4;
    const int ty4 = (tid >> 4) * 4;
    const int ldr = tid >> 2;        // 0..63 (row within half-tile)
    const int ldk = (tid & 3) * 4;   // 0,4,8,12 (k offset, float4)
    const int m0 = blockIdx.y * 128;
    const int n0 = blockIdx.x * 128;

    float acc[2][2][4][4];
#pragma unroll
    for (int qm = 0; qm < 2; ++qm)
#pragma unroll
        for (int qn = 0; qn < 2; ++qn)
#pragma unroll
            for (int i = 0; i < 4; ++i)
#pragma unroll
                for (int j = 0; j < 4; ++j) acc[qm][qn][i][j] = 0.f;

    const int gm0 = m0 + ldr;
    const int gm1 = m0 + ldr + 64;
    const int gn0 = n0 + ldr;
    const int gn1 = n0 + ldr + 64;

    // ---- main K loop over the dense weight (64 tiles of 16) ----
#pragma unroll 1
    for (int kt = 0; kt < 64; ++kt) {
        const int k0 = kt * 16 + ldk;
        float4 xv0 = make_float4(0.f, 0.f, 0.f, 0.f), xv1 = xv0;
        if (gm0 < MTOT) xv0 = ld4(&X[(size_t)gm0 * DD + k0]);
        if (gm1 < MTOT) xv1 = ld4(&X[(size_t)gm1 * DD + k0]);
        float4 wv0 = ld4(&W[(size_t)gn0 * DD + k0]);
        float4 wv1 = ld4(&W[(size_t)gn1 * DD + k0]);
        __syncthreads();
        As[ldk + 0][ldr] = xv0.x; As[ldk + 1][ldr] = xv0.y;
        As[ldk + 2][ldr] = xv0.z; As[ldk + 3][ldr] = xv0.w;
        As[ldk + 0][ldr + 64] = xv1.x; As[ldk + 1][ldr + 64] = xv1.y;
        As[ldk + 2][ldr + 64] = xv1.z; As[ldk + 3][ldr + 64] = xv1.w;
        Bs[ldk + 0][ldr] = wv0.x; Bs[ldk + 1][ldr] = wv0.y;
        Bs[ldk + 2][ldr] = wv0.z; Bs[ldk + 3][ldr] = wv0.w;
        Bs[ldk + 0][ldr + 64] = wv1.x; Bs[ldk + 1][ldr + 64] = wv1.y;
        Bs[ldk + 2][ldr + 64] = wv1.z; Bs[ldk + 3][ldr + 64] = wv1.w;
        __syncthreads();
        COMPUTE_TILE();
    }

    // ---- LoRA expert tail: up to 2 batch indices span this m-tile ----
    const int b_first = m0 / SS;
    const int b_last = ((m0 + 127 < MTOT ? m0 + 127 : MTOT - 1)) / SS;
#pragma unroll 1
    for (int bp = b_first; bp <= b_last; ++bp) {
#pragma unroll 1
        for (int ke = 0; ke < KEXP; ++ke) {
            const int e = idx[bp * KEXP + ke];
            float4 xv0 = make_float4(0.f, 0.f, 0.f, 0.f), xv1 = xv0;
            if (gm0 < MTOT && (gm0 / SS) == bp)
                xv0 = ld4(&xa[gm0 * (KEXP * RR) + ke * RR + ldk]);
            if (gm1 < MTOT && (gm1 / SS) == bp)
                xv1 = ld4(&xa[gm1 * (KEXP * RR) + ke * RR + ldk]);
            float4 bv0 = ld4(&Ball[(size_t)(e * DD + gn0) * RR + ldk]);
            float4 bv1 = ld4(&Ball[(size_t)(e * DD + gn1) * RR + ldk]);
            __syncthreads();
            As[ldk + 0][ldr] = xv0.x; As[ldk + 1][ldr] = xv0.y;
            As[ldk + 2][ldr] = xv0.z; As[ldk + 3][ldr] = xv0.w;
            As[ldk + 0][ldr + 64] = xv1.x; As[ldk + 1][ldr + 64] = xv1.y;
            As[ldk + 2][ldr + 64] = xv1.z; As[ldk + 3][ldr + 64] = xv1.w;
            Bs[ldk + 0][ldr] = bv0.x; Bs[ldk + 1][ldr] = bv0.y;
            Bs[ldk + 2][ldr] = bv0.z; Bs[ldk + 3][ldr] = bv0.w;
            Bs[ldk + 0][ldr + 64] = bv1.x; Bs[ldk + 1][ldr + 64] = bv1.y;
            Bs[ldk + 2][ldr + 64] = bv1.z; Bs[ldk + 3][ldr + 64] = bv1.w;
            __syncthreads();
            COMPUTE_TILE();
        }
    }

    // ---- epilogue: + bias, * alpha ----
#pragma unroll
    for (int qm = 0; qm < 2; ++qm)
#pragma unroll
        for (int i = 0; i < 4; ++i) {
            int gm = m0 + qm * 64 + (ty4 >> 2) * 4 + i; // = m0+qm*64+ty4+i
            gm = m0 + qm * 64 + ty4 + i;
            if (gm >= MTOT) continue;
#pragma unroll
            for (int qn = 0; qn < 2; ++qn) {
                int gn = n0 + qn * 64 + tx4;
                float4 b4 = ld4(&bias[gn]);
                float4 r;
                r.x = alpha * (acc[qm][qn][i][0] + b4.x);
                r.y = alpha * (acc[qm][qn][i][1] + b4.y);
                r.z = alpha * (acc[qm][qn][i][2] + b4.z);
                r.w = alpha * (acc[qm][qn][i][3] + b4.w);
                *(float4*)&C[(size_t)gm * DD + gn] = r;
            }
        }
}

// ---------------------------------------------------------------------------
// Attention: softmax(q k^T) v per (b, h), q pre-scaled. Writes in-place to q.
// grid: (9 q-tiles of 32, H, B), block 256. LDS ~58 KB.
// ---------------------------------------------------------------------------
__global__ __launch_bounds__(256) void attn_kernel(
    float* __restrict__ q, const float* __restrict__ kbuf,
    const float* __restrict__ vbuf)
{
    __shared__ float Qs[32][68];  // stride 68: float4-aligned
    __shared__ float KV[64][68];  // K tiles in pass 1, V tiles in pass 2
    __shared__ float L[32][260];  // full logit/prob rows (257 + pad)
    const int tid = threadIdx.x;
    const int b = blockIdx.z, h = blockIdx.y;
    const int s0 = blockIdx.x * 32;
    const int cb = h * HDIM;

    for (int i = tid; i < 32 * 64; i += 256) {
        int r = i >> 6, d = i & 63;
        int sg = s0 + r;
        Qs[r][d] = (sg < SS) ? q[(size_t)(b * SS + sg) * DD + cb + d] : 0.f;
    }

    const int tl = tid & 63;
    const int rb = tid >> 6; // 0..3

    // ---- pass 1: logits ----
    for (int tt = 0; tt < 5; ++tt) {
        const int t0 = tt * 64;
        __syncthreads();
        for (int i = tid; i < 64 * 64; i += 256) {
            int t = i >> 6, d = i & 63;
            int tg = t0 + t;
            KV[t][d] = (tg < SS) ? kbuf[(size_t)(b * SS + tg) * DD + cb + d]
                                 : 0.f;
        }
        __syncthreads();
        if (t0 + tl < SS) {
            float a8[8] = {0.f, 0.f, 0.f, 0.f, 0.f, 0.f, 0.f, 0.f};
#pragma unroll 4
            for (int d = 0; d < 64; d += 4) {
                float4 kv = ld4(&KV[tl][d]);
#pragma unroll
                for (int j = 0; j < 8; ++j) {
                    float4 qv = ld4(&Qs[rb * 8 + j][d]);
                    a8[j] = fmaf(qv.x, kv.x, a8[j]);
                    a8[j] = fmaf(qv.y, kv.y, a8[j]);
                    a8[j] = fmaf(qv.z, kv.z, a8[j]);
                    a8[j] = fmaf(qv.w, kv.w, a8[j]);
                }
            }
#pragma unroll
            for (int j = 0; j < 8; ++j) L[rb * 8 + j][t0 + tl] = a8[j];
        }
    }
    __syncthreads();

    // ---- softmax (8 lanes per row) ----
    {
        int r = tid >> 3, g = tid & 7;
        float mx = -1e30f;
        for (int t = g; t < SS; t += 8) mx = fmaxf(mx, L[r][t]);
        mx = fmaxf(mx, __shfl_xor(mx, 1, 8));
        mx = fmaxf(mx, __shfl_xor(mx, 2, 8));
        mx = fmaxf(mx, __shfl_xor(mx, 4, 8));
        float sum = 0.f;
        for (int t = g; t < SS; t += 8) {
            float p = __expf(L[r][t] - mx);
            L[r][t] = p;
            sum += p;
        }
        sum += __shfl_xor(sum, 1, 8);
        sum += __shfl_xor(sum, 2, 8);
        sum += __shfl_xor(sum, 4, 8);
        float inv = 1.f / sum;
        for (int t = g; t < SS; t += 8) L[r][t] *= inv;
        if (g < 3) L[r][257 + g] = 0.f; // zero pad cols for float4 tail reads
    }

    // ---- pass 2: P @ V ----
    const int d = tid & 63;
    float o8[8] = {0.f, 0.f, 0.f, 0.f, 0.f, 0.f, 0.f, 0.f};
    for (int tt = 0; tt < 5; ++tt) {
        const int t0 = tt * 64;
        __syncthreads();
        for (int i = tid; i < 64 * 64; i += 256) {
            int t = i >> 6, d2 = i & 63;
            int tg = t0 + t;
            KV[t][d2] = (tg < SS) ? vbuf[(size_t)(b * SS + tg) * DD + cb + d2]
                                  : 0.f;
        }
        __syncthreads();
        int lim = SS - t0;
        if (lim > 64) lim = 64;
#pragma unroll 2
        for (int tk = 0; tk < lim; tk += 4) {
            float v0 = KV[tk + 0][d];
            float v1 = KV[tk + 1][d];
            float v2 = KV[tk + 2][d];
            float v3 = KV[tk + 3][d];
#pragma unroll
            for (int j = 0; j < 8; ++j) {
                float4 p = ld4(&L[rb * 8 + j][t0 + tk]);
                o8[j] = fmaf(p.x, v0, o8[j]);
                o8[j] = fmaf(p.y, v1, o8[j]);
                o8[j] = fmaf(p.z, v2, o8[j]);
                o8[j] = fmaf(p.w, v3, o8[j]);
            }
        }
    }
#pragma unroll
    for (int j = 0; j < 8; ++j) {
        int sg = s0 + rb * 8 + j;
        if (sg < SS) q[(size_t)(b * SS + sg) * DD + cb + d] = o8[j];
    }
}

// ---------------------------------------------------------------------------
extern "C" void kernel_launch(void* const* d_in, const int* in_sizes, int n_in,
                              void* d_out, int out_size, void* d_ws,
                              size_t ws_size, hipStream_t stream)
{
    const float* hidden = (const float*)d_in[0];
    const int* tki = (const int*)d_in[1];
    const float* tkg = (const float*)d_in[2];
    const float* wq = (const float*)d_in[3];
    const float* Aq = (const float*)d_in[4];
    const float* Bq = (const float*)d_in[5];
    const float* bq = (const float*)d_in[6];
    const float* wk = (const float*)d_in[7];
    const float* Ak = (const float*)d_in[8];
    const float* Bk = (const float*)d_in[9];
    const float* bkb = (const float*)d_in[10];
    const float* wv = (const float*)d_in[11];
    const float* Av = (const float*)d_in[12];
    const float* Bv = (const float*)d_in[13];
    const float* bvb = (const float*)d_in[14];
    const float* wo = (const float*)d_in[15];
    const float* Ao = (const float*)d_in[16];
    const float* Bo = (const float*)d_in[17];
    const float* bob = (const float*)d_in[18];
    float* out = (float*)d_out;

    float* ws = (float*)d_ws;
    const size_t MD = (size_t)MTOT * DD;       // 8,421,376 floats
    const size_t XA = (size_t)MTOT * KEXP * RR; // 263,168 floats
    float* qbuf = ws;            // q, then attention output (in-place)
    float* vbuf = ws + MD;
    float* xaq = ws + 2 * MD;
    float* xak = xaq + XA;
    float* xav = xak + XA;
    float* xao = xav + XA;
    float* kbuf = out; // k projection parked in d_out (dead before final GEMM)

    dim3 blk(256);
    dim3 gxa(17, BB * KEXP);
    dim3 ggemm(8, 65);
    dim3 gattn(9, HH, BB);

    xa_kernel<<<gxa, blk, 0, stream>>>(hidden, Aq, tki, tkg, xaq);
    xa_kernel<<<gxa, blk, 0, stream>>>(hidden, Ak, tki, tkg, xak);
    xa_kernel<<<gxa, blk, 0, stream>>>(hidden, Av, tki, tkg, xav);
    gemm_lora<<<ggemm, blk, 0, stream>>>(hidden, wq, bq, xaq, Bq, tki, qbuf,
                                         0.125f); // SCALE folded into q
    gemm_lora<<<ggemm, blk, 0, stream>>>(hidden, wk, bkb, xak, Bk, tki, kbuf,
                                         1.0f);
    gemm_lora<<<ggemm, blk, 0, stream>>>(hidden, wv, bvb, xav, Bv, tki, vbuf,
                                         1.0f);
    attn_kernel<<<gattn, blk, 0, stream>>>(qbuf, kbuf, vbuf);
    xa_kernel<<<gxa, blk, 0, stream>>>(qbuf, Ao, tki, tkg, xao);
    gemm_lora<<<ggemm, blk, 0, stream>>>(qbuf, wo, bob, xao, Bo, tki, out,
                                         1.0f);
}

// Round 3
// 1927.750 us; speedup vs baseline: 1.4037x; 1.4037x over previous
//
#include <hip/hip_runtime.h>

// ViTMoEAttention: B=32,S=257,D=1024,H=16,HD=64,E=8,R=16,K=2
// Round 3: fix round-2 LoRA-tail staging bug (uint4 = 8 ushorts; tail wrote
// only half of each 32-wide LDS row, leaving stale X/W garbage in cols
// 8-15/24-31 -> absmax 7e-2). Now each tail thread writes two uint4s.
// GEMMs: split-bf16 (hi/lo) MFMA, 3 products: xh*wh + xh*wl + xl*wh.
// m97-style: 128x128 tile, BK=32, global_load_lds w=16, 16x16x32 bf16 MFMA.

#define BB 32
#define SS 257
#define DD 1024
#define HH 16
#define HDIM 64
#define EE 8
#define RR 16
#define KEXP 2
#define MTOT (BB * SS)   // 8224
#define MPAD 8320        // 65 * 128

typedef __attribute__((ext_vector_type(8))) short bf16x8;
typedef __attribute__((ext_vector_type(4))) float f32x4;

static __device__ __forceinline__ float4 ld4(const float* p) {
    return *(const float4*)p;
}

// split fp32 -> bf16 hi + bf16 lo (RNE both)
static __device__ __forceinline__ void split1(float x, unsigned short& h,
                                              unsigned short& l) {
    unsigned int ux = __float_as_uint(x);
    unsigned int hb = (ux + 0x7FFFu + ((ux >> 16) & 1u)) >> 16;
    float hf = __uint_as_float(hb << 16);
    float lo = x - hf; // exact
    unsigned int ul = __float_as_uint(lo);
    unsigned int lb = (ul + 0x7FFFu + ((ul >> 16) & 1u)) >> 16;
    h = (unsigned short)hb;
    l = (unsigned short)lb;
}

static __device__ __forceinline__ void gl_lds16(const unsigned short* g,
                                                unsigned short* l) {
    __builtin_amdgcn_global_load_lds(
        (const __attribute__((address_space(1))) unsigned int*)g,
        (__attribute__((address_space(3))) unsigned int*)l, 16, 0, 0);
}

// ---------------------------------------------------------------------------
// split_kernel: fp32 src -> bf16 hi/lo arrays; pads [nvalid, ntotal) with 0.
// ---------------------------------------------------------------------------
__global__ __launch_bounds__(256) void split_kernel(
    const float* __restrict__ src, unsigned short* __restrict__ h,
    unsigned short* __restrict__ l, long nvalid, long ntotal)
{
    long i = ((long)blockIdx.x * 256 + threadIdx.x) * 4;
    if (i >= ntotal) return;
    float4 v = (i < nvalid) ? ld4(&src[i]) : make_float4(0.f, 0.f, 0.f, 0.f);
    ushort4 hv, lv;
    split1(v.x, hv.x, lv.x);
    split1(v.y, hv.y, lv.y);
    split1(v.z, hv.z, lv.z);
    split1(v.w, hv.w, lv.w);
    *(ushort4*)&h[i] = hv;
    *(ushort4*)&l[i] = lv;
}

// ---------------------------------------------------------------------------
// xa[m][ke*16+r] = gates[b][ke] * sum_d X[m][d] * A[idx[b][ke]][r][d]
// output bf16 hi/lo. grid: (17, B*KEXP), block 256 = (r=16) x (s=16)
// ---------------------------------------------------------------------------
__global__ __launch_bounds__(256) void xa_kernel(
    const float* __restrict__ X, const float* __restrict__ A,
    const int* __restrict__ idx, const float* __restrict__ gates,
    unsigned short* __restrict__ xah, unsigned short* __restrict__ xal)
{
    int bk2 = blockIdx.y;
    int b = bk2 >> 1, ke = bk2 & 1;
    int r = threadIdx.x & 15;
    int si = threadIdx.x >> 4;
    int s = blockIdx.x * 16 + si;
    if (s >= SS) return;
    int e = idx[b * KEXP + ke];
    float g = gates[b * KEXP + ke];
    const float* xrow = X + (size_t)(b * SS + s) * DD;
    const float* arow = A + (size_t)(e * RR + r) * DD;
    float acc = 0.f;
#pragma unroll 8
    for (int d = 0; d < DD; d += 4) {
        float4 xv = ld4(xrow + d);
        float4 av = ld4(arow + d);
        acc = fmaf(xv.x, av.x, acc);
        acc = fmaf(xv.y, av.y, acc);
        acc = fmaf(xv.z, av.z, acc);
        acc = fmaf(xv.w, av.w, acc);
    }
    float val = g * acc;
    unsigned short h, l;
    split1(val, h, l);
    size_t o = (size_t)(b * SS + s) * (KEXP * RR) + ke * RR + r;
    xah[o] = h;
    xal[o] = l;
}

// ---------------------------------------------------------------------------
// Bcat[b][n][ke*16+r] = Ball[idx[b][ke]][n][r]  (bf16 hi/lo)
// ---------------------------------------------------------------------------
__global__ __launch_bounds__(256) void bcat_kernel(
    const float* __restrict__ Ball, const int* __restrict__ idx,
    unsigned short* __restrict__ h, unsigned short* __restrict__ l)
{
    int b = blockIdx.y;
    int i = blockIdx.x * 256 + threadIdx.x; // 0..32767
    int n = i >> 5, kk = i & 31;
    int ke = kk >> 4, r = kk & 15;
    int e = idx[b * KEXP + ke];
    float x = Ball[((size_t)e * DD + n) * RR + r];
    unsigned short hh, ll;
    split1(x, hh, ll);
    size_t o = ((size_t)b * DD + n) * (KEXP * RR) + kk;
    h[o] = hh;
    l[o] = ll;
}

// ---------------------------------------------------------------------------
// MFMA GEMM: C[m][n] = alpha*(sum_d X[m][d]W[n][d] + expert + bias[n])
// 128x128 tile, BK=32, 4 waves (2x2 of 64x64), 16x16x32 bf16 MFMA,
// 3 hi/lo products. grid: (8, 65), block 256.
// ---------------------------------------------------------------------------
#define COMPUTE_CHUNK()                                                        \
    do {                                                                       \
        bf16x8 afh[4], afl[4], bfh[4], bfl[4];                                 \
        _Pragma("unroll") for (int t = 0; t < 4; ++t) {                        \
            int ar = wm + t * 16 + l16;                                        \
            int br = wn + t * 16 + l16;                                        \
            afh[t] = *(const bf16x8*)&Ah[ar * 32 + quad * 8];                  \
            afl[t] = *(const bf16x8*)&Al[ar * 32 + quad * 8];                  \
            bfh[t] = *(const bf16x8*)&Bh[br * 32 + quad * 8];                  \
            bfl[t] = *(const bf16x8*)&Bl[br * 32 + quad * 8];                  \
        }                                                                      \
        _Pragma("unroll") for (int i = 0; i < 4; ++i)                          \
        _Pragma("unroll") for (int j = 0; j < 4; ++j) {                        \
            acc[i][j] = __builtin_amdgcn_mfma_f32_16x16x32_bf16(               \
                afh[i], bfh[j], acc[i][j], 0, 0, 0);                           \
            acc[i][j] = __builtin_amdgcn_mfma_f32_16x16x32_bf16(               \
                afh[i], bfl[j], acc[i][j], 0, 0, 0);                           \
            acc[i][j] = __builtin_amdgcn_mfma_f32_16x16x32_bf16(               \
                afl[i], bfh[j], acc[i][j], 0, 0, 0);                           \
        }                                                                      \
    } while (0)

__global__ __launch_bounds__(256) void gemm_mfma(
    const unsigned short* __restrict__ Xh, const unsigned short* __restrict__ Xl,
    const unsigned short* __restrict__ Wh, const unsigned short* __restrict__ Wl,
    const float* __restrict__ bias,
    const unsigned short* __restrict__ xah, const unsigned short* __restrict__ xal,
    const unsigned short* __restrict__ Bch, const unsigned short* __restrict__ Bcl,
    float* __restrict__ C, float alpha)
{
    __shared__ unsigned short Ah[128 * 32];
    __shared__ unsigned short Al[128 * 32];
    __shared__ unsigned short Bh[128 * 32];
    __shared__ unsigned short Bl[128 * 32];

    const int tid = threadIdx.x;
    const int m0 = blockIdx.y * 128;
    const int n0 = blockIdx.x * 128;
    const int lane = tid & 63;
    const int w = tid >> 6;
    const int wm = (w >> 1) * 64;
    const int wn = (w & 1) * 64;
    const int l16 = lane & 15;
    const int quad = lane >> 4;

    f32x4 acc[4][4];
#pragma unroll
    for (int i = 0; i < 4; ++i)
#pragma unroll
        for (int j = 0; j < 4; ++j) acc[i][j] = (f32x4){0.f, 0.f, 0.f, 0.f};

    // staging geometry: per call, 256 threads x 16B = 64 rows x 64B
    const int srow = tid >> 2;
    const int scol = (tid & 3) * 8;              // ushort offset in 32-wide row
    const int lbase = (tid & 192) * 8;           // wave-uniform LDS ushort base
    const size_t xr0 = (size_t)(m0 + srow) * DD + scol;
    const size_t xr1 = (size_t)(m0 + srow + 64) * DD + scol;
    const size_t wr0 = (size_t)(n0 + srow) * DD + scol;
    const size_t wr1 = (size_t)(n0 + srow + 64) * DD + scol;

#pragma unroll 1
    for (int kt = 0; kt < 32; ++kt) {
        const int k0 = kt * 32;
        gl_lds16(Xh + xr0 + k0, &Ah[lbase]);
        gl_lds16(Xh + xr1 + k0, &Ah[2048 + lbase]);
        gl_lds16(Xl + xr0 + k0, &Al[lbase]);
        gl_lds16(Xl + xr1 + k0, &Al[2048 + lbase]);
        gl_lds16(Wh + wr0 + k0, &Bh[lbase]);
        gl_lds16(Wh + wr1 + k0, &Bh[2048 + lbase]);
        gl_lds16(Wl + wr0 + k0, &Bl[lbase]);
        gl_lds16(Wl + wr1 + k0, &Bl[2048 + lbase]);
        __syncthreads();
        COMPUTE_CHUNK();
        __syncthreads();
    }

    // ---- LoRA expert tail: one masked K=32 chunk per batch in this m-tile
    // Each thread covers 16 ushorts (two uint4s) per array: r = tid>>1,
    // cols [c, c+16) with c = (tid&1)*16. (Round-2 bug: only wrote 8.)
    {
        int m_hi = m0 + 127;
        if (m_hi >= MTOT) m_hi = MTOT - 1;
        const int b_first = m0 / SS;
        const int b_last = m_hi / SS;
        const int r = tid >> 1;
        const int c = (tid & 1) * 16;
#pragma unroll 1
        for (int bp = b_first; bp <= b_last; ++bp) {
            const int gm = m0 + r;
            const bool va = (gm < MTOT) && (gm / SS == bp);
            uint4 avh0 = make_uint4(0, 0, 0, 0), avh1 = avh0;
            uint4 avl0 = avh0, avl1 = avh0;
            if (va) {
                avh0 = *(const uint4*)&xah[(size_t)gm * 32 + c];
                avh1 = *(const uint4*)&xah[(size_t)gm * 32 + c + 8];
                avl0 = *(const uint4*)&xal[(size_t)gm * 32 + c];
                avl1 = *(const uint4*)&xal[(size_t)gm * 32 + c + 8];
            }
            const int gn = n0 + r;
            const size_t bo = ((size_t)bp * DD + gn) * 32 + c;
            uint4 bvh0 = *(const uint4*)&Bch[bo];
            uint4 bvh1 = *(const uint4*)&Bch[bo + 8];
            uint4 bvl0 = *(const uint4*)&Bcl[bo];
            uint4 bvl1 = *(const uint4*)&Bcl[bo + 8];
            __syncthreads();
            *(uint4*)&Ah[r * 32 + c] = avh0;
            *(uint4*)&Ah[r * 32 + c + 8] = avh1;
            *(uint4*)&Al[r * 32 + c] = avl0;
            *(uint4*)&Al[r * 32 + c + 8] = avl1;
            *(uint4*)&Bh[r * 32 + c] = bvh0;
            *(uint4*)&Bh[r * 32 + c + 8] = bvh1;
            *(uint4*)&Bl[r * 32 + c] = bvl0;
            *(uint4*)&Bl[r * 32 + c + 8] = bvl1;
            __syncthreads();
            COMPUTE_CHUNK();
            __syncthreads();
        }
    }

    // ---- epilogue: + bias, * alpha. C layout: col=lane&15, row=quad*4+reg
#pragma unroll
    for (int j = 0; j < 4; ++j) {
        const int n = n0 + wn + j * 16 + l16;
        const float bv = bias[n];
#pragma unroll
        for (int i = 0; i < 4; ++i) {
            const int mb = m0 + wm + i * 16 + quad * 4;
#pragma unroll
            for (int rg = 0; rg < 4; ++rg) {
                const int m = mb + rg;
                if (m < MTOT)
                    C[(size_t)m * DD + n] = alpha * (acc[i][j][rg] + bv);
            }
        }
    }
}

// ---------------------------------------------------------------------------
// Attention (unchanged): softmax(q k^T) v per (b,h), in-place q.
// ---------------------------------------------------------------------------
__global__ __launch_bounds__(256) void attn_kernel(
    float* __restrict__ q, const float* __restrict__ kbuf,
    const float* __restrict__ vbuf)
{
    __shared__ float Qs[32][68];
    __shared__ float KV[64][68];
    __shared__ float L[32][260];
    const int tid = threadIdx.x;
    const int b = blockIdx.z, h = blockIdx.y;
    const int s0 = blockIdx.x * 32;
    const int cb = h * HDIM;

    for (int i = tid; i < 32 * 64; i += 256) {
        int r = i >> 6, d = i & 63;
        int sg = s0 + r;
        Qs[r][d] = (sg < SS) ? q[(size_t)(b * SS + sg) * DD + cb + d] : 0.f;
    }

    const int tl = tid & 63;
    const int rb = tid >> 6;

    for (int tt = 0; tt < 5; ++tt) {
        const int t0 = tt * 64;
        __syncthreads();
        for (int i = tid; i < 64 * 64; i += 256) {
            int t = i >> 6, d = i & 63;
            int tg = t0 + t;
            KV[t][d] = (tg < SS) ? kbuf[(size_t)(b * SS + tg) * DD + cb + d]
                                 : 0.f;
        }
        __syncthreads();
        if (t0 + tl < SS) {
            float a8[8] = {0.f, 0.f, 0.f, 0.f, 0.f, 0.f, 0.f, 0.f};
#pragma unroll 4
            for (int d = 0; d < 64; d += 4) {
                float4 kv = ld4(&KV[tl][d]);
#pragma unroll
                for (int j = 0; j < 8; ++j) {
                    float4 qv = ld4(&Qs[rb * 8 + j][d]);
                    a8[j] = fmaf(qv.x, kv.x, a8[j]);
                    a8[j] = fmaf(qv.y, kv.y, a8[j]);
                    a8[j] = fmaf(qv.z, kv.z, a8[j]);
                    a8[j] = fmaf(qv.w, kv.w, a8[j]);
                }
            }
#pragma unroll
            for (int j = 0; j < 8; ++j) L[rb * 8 + j][t0 + tl] = a8[j];
        }
    }
    __syncthreads();

    {
        int r = tid >> 3, g = tid & 7;
        float mx = -1e30f;
        for (int t = g; t < SS; t += 8) mx = fmaxf(mx, L[r][t]);
        mx = fmaxf(mx, __shfl_xor(mx, 1, 8));
        mx = fmaxf(mx, __shfl_xor(mx, 2, 8));
        mx = fmaxf(mx, __shfl_xor(mx, 4, 8));
        float sum = 0.f;
        for (int t = g; t < SS; t += 8) {
            float p = __expf(L[r][t] - mx);
            L[r][t] = p;
            sum += p;
        }
        sum += __shfl_xor(sum, 1, 8);
        sum += __shfl_xor(sum, 2, 8);
        sum += __shfl_xor(sum, 4, 8);
        float inv = 1.f / sum;
        for (int t = g; t < SS; t += 8) L[r][t] *= inv;
        if (g < 3) L[r][257 + g] = 0.f;
    }

    const int d = tid & 63;
    float o8[8] = {0.f, 0.f, 0.f, 0.f, 0.f, 0.f, 0.f, 0.f};
    for (int tt = 0; tt < 5; ++tt) {
        const int t0 = tt * 64;
        __syncthreads();
        for (int i = tid; i < 64 * 64; i += 256) {
            int t = i >> 6, d2 = i & 63;
            int tg = t0 + t;
            KV[t][d2] = (tg < SS) ? vbuf[(size_t)(b * SS + tg) * DD + cb + d2]
                                  : 0.f;
        }
        __syncthreads();
        int lim = SS - t0;
        if (lim > 64) lim = 64;
#pragma unroll 2
        for (int tk = 0; tk < lim; tk += 4) {
            float v0 = KV[tk + 0][d];
            float v1 = KV[tk + 1][d];
            float v2 = KV[tk + 2][d];
            float v3 = KV[tk + 3][d];
#pragma unroll
            for (int j = 0; j < 8; ++j) {
                float4 p = ld4(&L[rb * 8 + j][t0 + tk]);
                o8[j] = fmaf(p.x, v0, o8[j]);
                o8[j] = fmaf(p.y, v1, o8[j]);
                o8[j] = fmaf(p.z, v2, o8[j]);
                o8[j] = fmaf(p.w, v3, o8[j]);
            }
        }
    }
#pragma unroll
    for (int j = 0; j < 8; ++j) {
        int sg = s0 + rb * 8 + j;
        if (sg < SS) q[(size_t)(b * SS + sg) * DD + cb + d] = o8[j];
    }
}

// ---------------------------------------------------------------------------
extern "C" void kernel_launch(void* const* d_in, const int* in_sizes, int n_in,
                              void* d_out, int out_size, void* d_ws,
                              size_t ws_size, hipStream_t stream)
{
    const float* hidden = (const float*)d_in[0];
    const int* tki = (const int*)d_in[1];
    const float* tkg = (const float*)d_in[2];
    const float* wq = (const float*)d_in[3];
    const float* Aq = (const float*)d_in[4];
    const float* Bq = (const float*)d_in[5];
    const float* bq = (const float*)d_in[6];
    const float* wk = (const float*)d_in[7];
    const float* Ak = (const float*)d_in[8];
    const float* Bk = (const float*)d_in[9];
    const float* bkb = (const float*)d_in[10];
    const float* wv = (const float*)d_in[11];
    const float* Av = (const float*)d_in[12];
    const float* Bv = (const float*)d_in[13];
    const float* bvb = (const float*)d_in[14];
    const float* wo = (const float*)d_in[15];
    const float* Ao = (const float*)d_in[16];
    const float* Bo = (const float*)d_in[17];
    const float* bob = (const float*)d_in[18];
    float* out = (float*)d_out;

    // ---- workspace carve-up (bytes) ----
    char* ws = (char*)d_ws;
    const size_t MD_F = (size_t)MTOT * DD * 4;      // 33.7 MB fp32
    const size_t MPD_H = (size_t)MPAD * DD * 2;     // 17.0 MB bf16 (padded)
    const size_t XA_H = (size_t)MPAD * 32 * 2;      // 0.53 MB
    const size_t W_H = (size_t)DD * DD * 2;         // 2.1 MB
    const size_t BC_H = (size_t)BB * DD * 32 * 2;   // 2.1 MB

    float* qbuf = (float*)ws;               ws += MD_F;
    float* vbuf = (float*)ws;               ws += MD_F;
    unsigned short* Xh = (unsigned short*)ws; ws += MPD_H;
    unsigned short* Xl = (unsigned short*)ws; ws += MPD_H;
    unsigned short* Wh = (unsigned short*)ws; ws += W_H;
    unsigned short* Wl = (unsigned short*)ws; ws += W_H;
    unsigned short* Bch = (unsigned short*)ws; ws += BC_H;
    unsigned short* Bcl = (unsigned short*)ws; ws += BC_H;
    unsigned short* xah = (unsigned short*)ws; ws += XA_H;
    unsigned short* xal = (unsigned short*)ws; ws += XA_H;
    float* kbuf = out; // k projection parked in d_out (dead before final GEMM)

    const long NX_V = (long)MTOT * DD, NX_T = (long)MPAD * DD;
    const long NW = (long)DD * DD;

    dim3 blk(256);
    dim3 gsX(NX_T / 1024);
    dim3 gsW(NW / 1024);
    dim3 gxa(17, BB * KEXP);
    dim3 gbc(128, BB);
    dim3 ggemm(8, 65);
    dim3 gattn(9, HH, BB);

    // X -> hi/lo
    split_kernel<<<gsX, blk, 0, stream>>>(hidden, Xh, Xl, NX_V, NX_T);

    // Q
    split_kernel<<<gsW, blk, 0, stream>>>(wq, Wh, Wl, NW, NW);
    bcat_kernel<<<gbc, blk, 0, stream>>>(Bq, tki, Bch, Bcl);
    xa_kernel<<<gxa, blk, 0, stream>>>(hidden, Aq, tki, tkg, xah, xal);
    gemm_mfma<<<ggemm, blk, 0, stream>>>(Xh, Xl, Wh, Wl, bq, xah, xal, Bch,
                                         Bcl, qbuf, 0.125f);
    // K
    split_kernel<<<gsW, blk, 0, stream>>>(wk, Wh, Wl, NW, NW);
    bcat_kernel<<<gbc, blk, 0, stream>>>(Bk, tki, Bch, Bcl);
    xa_kernel<<<gxa, blk, 0, stream>>>(hidden, Ak, tki, tkg, xah, xal);
    gemm_mfma<<<ggemm, blk, 0, stream>>>(Xh, Xl, Wh, Wl, bkb, xah, xal, Bch,
                                         Bcl, kbuf, 1.0f);
    // V
    split_kernel<<<gsW, blk, 0, stream>>>(wv, Wh, Wl, NW, NW);
    bcat_kernel<<<gbc, blk, 0, stream>>>(Bv, tki, Bch, Bcl);
    xa_kernel<<<gxa, blk, 0, stream>>>(hidden, Av, tki, tkg, xah, xal);
    gemm_mfma<<<ggemm, blk, 0, stream>>>(Xh, Xl, Wh, Wl, bvb, xah, xal, Bch,
                                         Bcl, vbuf, 1.0f);

    // attention (in-place on qbuf)
    attn_kernel<<<gattn, blk, 0, stream>>>(qbuf, kbuf, vbuf);

    // O projection: split attn output into Xh/Xl (reuse), xa from attn out
    split_kernel<<<gsX, blk, 0, stream>>>(qbuf, Xh, Xl, NX_V, NX_T);
    split_kernel<<<gsW, blk, 0, stream>>>(wo, Wh, Wl, NW, NW);
    bcat_kernel<<<gbc, blk, 0, stream>>>(Bo, tki, Bch, Bcl);
    xa_kernel<<<gxa, blk, 0, stream>>>(qbuf, Ao, tki, tkg, xah, xal);
    gemm_mfma<<<ggemm, blk, 0, stream>>>(Xh, Xl, Wh, Wl, bob, xah, xal, Bch,
                                         Bcl, out, 1.0f);
}

// Round 4
// 818.126 us; speedup vs baseline: 3.3076x; 2.3563x over previous
//
#include <hip/hip_runtime.h>

// ViTMoEAttention: B=32,S=257,D=1024,H=16,HD=64,E=8,R=16,K=2
// Round 4: (1) MFMA attention (bf16 QK^T + PV, full-row softmax in LDS),
// (2) q/k/v GEMMs emit bf16-hi directly; attn emits split Xh/Xl directly,
// (3) merged xa kernels (qkv share X reads; o reads Xh+Xl).
// Dense GEMMs: split-bf16 (hi/lo), 3 products; single-pass LoRA tail
// (xa hi-only x Bcat hi/lo).

#define BB 32
#define SS 257
#define DD 1024
#define HH 16
#define HDIM 64
#define EE 8
#define RR 16
#define KEXP 2
#define MTOT (BB * SS)   // 8224
#define MPAD 8320        // 65 * 128

typedef __attribute__((ext_vector_type(8))) short bf16x8;
typedef __attribute__((ext_vector_type(4))) float f32x4;

static __device__ __forceinline__ float4 ld4(const float* p) {
    return *(const float4*)p;
}

// fp32 -> bf16 (RNE)
static __device__ __forceinline__ unsigned short bf16h(float x) {
    unsigned int ux = __float_as_uint(x);
    return (unsigned short)((ux + 0x7FFFu + ((ux >> 16) & 1u)) >> 16);
}
static __device__ __forceinline__ float b2f(unsigned short v) {
    return __uint_as_float(((unsigned int)v) << 16);
}
// split fp32 -> bf16 hi + bf16 lo (RNE both)
static __device__ __forceinline__ void split1(float x, unsigned short& h,
                                              unsigned short& l) {
    unsigned int ux = __float_as_uint(x);
    unsigned int hb = (ux + 0x7FFFu + ((ux >> 16) & 1u)) >> 16;
    float hf = __uint_as_float(hb << 16);
    float lo = x - hf; // exact
    unsigned int ul = __float_as_uint(lo);
    unsigned int lb = (ul + 0x7FFFu + ((ul >> 16) & 1u)) >> 16;
    h = (unsigned short)hb;
    l = (unsigned short)lb;
}

static __device__ __forceinline__ void gl_lds16(const unsigned short* g,
                                                unsigned short* l) {
    __builtin_amdgcn_global_load_lds(
        (const __attribute__((address_space(1))) unsigned int*)g,
        (__attribute__((address_space(3))) unsigned int*)l, 16, 0, 0);
}

// ---------------------------------------------------------------------------
// split_kernel: fp32 src -> bf16 hi/lo arrays; pads [nvalid, ntotal) with 0.
// ---------------------------------------------------------------------------
__global__ __launch_bounds__(256) void split_kernel(
    const float* __restrict__ src, unsigned short* __restrict__ h,
    unsigned short* __restrict__ l, long nvalid, long ntotal)
{
    long i = ((long)blockIdx.x * 256 + threadIdx.x) * 4;
    if (i >= ntotal) return;
    float4 v = (i < nvalid) ? ld4(&src[i]) : make_float4(0.f, 0.f, 0.f, 0.f);
    ushort4 hv, lv;
    split1(v.x, hv.x, lv.x);
    split1(v.y, hv.y, lv.y);
    split1(v.z, hv.z, lv.z);
    split1(v.w, hv.w, lv.w);
    *(ushort4*)&h[i] = hv;
    *(ushort4*)&l[i] = lv;
}

// ---------------------------------------------------------------------------
// Bcat[b][n][ke*16+r] = Ball[idx[b][ke]][n][r]  (bf16 hi/lo)
// ---------------------------------------------------------------------------
__global__ __launch_bounds__(256) void bcat_kernel(
    const float* __restrict__ Ball, const int* __restrict__ idx,
    unsigned short* __restrict__ h, unsigned short* __restrict__ l)
{
    int b = blockIdx.y;
    int i = blockIdx.x * 256 + threadIdx.x; // 0..32767
    int n = i >> 5, kk = i & 31;
    int ke = kk >> 4, r = kk & 15;
    int e = idx[b * KEXP + ke];
    float x = Ball[((size_t)e * DD + n) * RR + r];
    unsigned short hh, ll;
    split1(x, hh, ll);
    size_t o = ((size_t)b * DD + n) * (KEXP * RR) + kk;
    h[o] = hh;
    l[o] = ll;
}

// ---------------------------------------------------------------------------
// xa_qkv: for (b,ke,s-tile of 64): xa_p[m][ke*16+r] = g * sum_d X[m][d]A_p[e][r][d]
// for p in {q,k,v} sharing the X reads. LDS-tiled, fp32 VALU. grid (5, 64).
// ---------------------------------------------------------------------------
__global__ __launch_bounds__(256) void xa_qkv(
    const float* __restrict__ X, const float* __restrict__ Aq,
    const float* __restrict__ Ak, const float* __restrict__ Av,
    const int* __restrict__ idx, const float* __restrict__ gates,
    unsigned short* __restrict__ xq, unsigned short* __restrict__ xk,
    unsigned short* __restrict__ xv)
{
    __shared__ float Xs[64][68];
    __shared__ float As[48][68];
    const int tid = threadIdx.x;
    const int bk = blockIdx.y;
    const int b = bk >> 1, ke = bk & 1;
    const int s0 = blockIdx.x * 64;
    const int e = idx[b * 2 + ke];
    const float g = gates[b * 2 + ke];
    const int tx = tid & 15, ty = tid >> 4;
    const int c4 = tx * 4;

    float acc[4][3];
#pragma unroll
    for (int a = 0; a < 4; ++a)
#pragma unroll
        for (int p = 0; p < 3; ++p) acc[a][p] = 0.f;

#pragma unroll 1
    for (int kt = 0; kt < 16; ++kt) {
        const int k0 = kt * 64;
        __syncthreads();
#pragma unroll
        for (int p = 0; p < 4; ++p) {
            int row = ty + p * 16;
            int sg = s0 + row;
            if (sg > SS - 1) sg = SS - 1;
            *(float4*)&Xs[row][c4] =
                ld4(&X[(size_t)(b * SS + sg) * DD + k0 + c4]);
        }
#pragma unroll
        for (int p = 0; p < 3; ++p) {
            const float* Ap = (p == 0) ? Aq : (p == 1) ? Ak : Av;
            *(float4*)&As[p * 16 + ty][c4] =
                ld4(&Ap[(size_t)(e * RR + ty) * DD + k0 + c4]);
        }
        __syncthreads();
#pragma unroll 4
        for (int k4 = 0; k4 < 16; ++k4) {
            float4 xr[4], ar[3];
#pragma unroll
            for (int a = 0; a < 4; ++a)
                xr[a] = *(float4*)&Xs[ty + 16 * a][k4 * 4];
#pragma unroll
            for (int p = 0; p < 3; ++p)
                ar[p] = *(float4*)&As[tx + 16 * p][k4 * 4];
#pragma unroll
            for (int a = 0; a < 4; ++a)
#pragma unroll
                for (int p = 0; p < 3; ++p) {
                    acc[a][p] = fmaf(xr[a].x, ar[p].x, acc[a][p]);
                    acc[a][p] = fmaf(xr[a].y, ar[p].y, acc[a][p]);
                    acc[a][p] = fmaf(xr[a].z, ar[p].z, acc[a][p]);
                    acc[a][p] = fmaf(xr[a].w, ar[p].w, acc[a][p]);
                }
        }
    }
#pragma unroll
    for (int a = 0; a < 4; ++a) {
        int sg = s0 + ty + 16 * a;
        if (sg < SS) {
            size_t o = (size_t)(b * SS + sg) * 32 + ke * RR + tx;
            xq[o] = bf16h(g * acc[a][0]);
            xk[o] = bf16h(g * acc[a][1]);
            xv[o] = bf16h(g * acc[a][2]);
        }
    }
}

// ---------------------------------------------------------------------------
// xa_o: same but X reconstructed from Xh+Xl (attn output), both ke in-block.
// grid (5, 32).
// ---------------------------------------------------------------------------
__global__ __launch_bounds__(256) void xa_o(
    const unsigned short* __restrict__ Xhb,
    const unsigned short* __restrict__ Xlb, const float* __restrict__ Ao,
    const int* __restrict__ idx, const float* __restrict__ gates,
    unsigned short* __restrict__ xo)
{
    __shared__ float Xs[64][68];
    __shared__ float As[32][68];
    const int tid = threadIdx.x;
    const int b = blockIdx.y;
    const int s0 = blockIdx.x * 64;
    const int e0 = idx[b * 2 + 0], e1 = idx[b * 2 + 1];
    const float g0 = gates[b * 2 + 0], g1 = gates[b * 2 + 1];
    const int tx = tid & 15, ty = tid >> 4;
    const int c4 = tx * 4;

    float acc[4][2];
#pragma unroll
    for (int a = 0; a < 4; ++a) {
        acc[a][0] = 0.f;
        acc[a][1] = 0.f;
    }

#pragma unroll 1
    for (int kt = 0; kt < 16; ++kt) {
        const int k0 = kt * 64;
        __syncthreads();
#pragma unroll
        for (int p = 0; p < 4; ++p) {
            int row = ty + p * 16;
            int sg = s0 + row;
            if (sg > SS - 1) sg = SS - 1;
            size_t off = (size_t)(b * SS + sg) * DD + k0 + c4;
            ushort4 hv = *(const ushort4*)&Xhb[off];
            ushort4 lv = *(const ushort4*)&Xlb[off];
            float4 xf;
            xf.x = b2f(hv.x) + b2f(lv.x);
            xf.y = b2f(hv.y) + b2f(lv.y);
            xf.z = b2f(hv.z) + b2f(lv.z);
            xf.w = b2f(hv.w) + b2f(lv.w);
            *(float4*)&Xs[row][c4] = xf;
        }
#pragma unroll
        for (int p = 0; p < 2; ++p) {
            int e = (p == 0) ? e0 : e1;
            *(float4*)&As[p * 16 + ty][c4] =
                ld4(&Ao[(size_t)(e * RR + ty) * DD + k0 + c4]);
        }
        __syncthreads();
#pragma unroll 4
        for (int k4 = 0; k4 < 16; ++k4) {
            float4 xr[4], ar[2];
#pragma unroll
            for (int a = 0; a < 4; ++a)
                xr[a] = *(float4*)&Xs[ty + 16 * a][k4 * 4];
#pragma unroll
            for (int p = 0; p < 2; ++p)
                ar[p] = *(float4*)&As[tx + 16 * p][k4 * 4];
#pragma unroll
            for (int a = 0; a < 4; ++a)
#pragma unroll
                for (int p = 0; p < 2; ++p) {
                    acc[a][p] = fmaf(xr[a].x, ar[p].x, acc[a][p]);
                    acc[a][p] = fmaf(xr[a].y, ar[p].y, acc[a][p]);
                    acc[a][p] = fmaf(xr[a].z, ar[p].z, acc[a][p]);
                    acc[a][p] = fmaf(xr[a].w, ar[p].w, acc[a][p]);
                }
        }
    }
#pragma unroll
    for (int a = 0; a < 4; ++a) {
        int sg = s0 + ty + 16 * a;
        if (sg < SS) {
            size_t o = (size_t)(b * SS + sg) * 32;
            xo[o + tx] = bf16h(g0 * acc[a][0]);
            xo[o + 16 + tx] = bf16h(g1 * acc[a][1]);
        }
    }
}

// ---------------------------------------------------------------------------
// MFMA GEMM: 128x128 tile, BK=32, split-bf16 3 products. Single-pass LoRA
// tail (xa hi x Bcat hi/lo; Al zeroed). Output: fp32 (Cf) or bf16-hi (Ch).
// grid: (8, 65), block 256.
// ---------------------------------------------------------------------------
#define COMPUTE_CHUNK()                                                        \
    do {                                                                       \
        bf16x8 afh[4], afl[4], bfh[4], bfl[4];                                 \
        _Pragma("unroll") for (int t = 0; t < 4; ++t) {                        \
            int ar = wm + t * 16 + l16;                                        \
            int br = wn + t * 16 + l16;                                        \
            afh[t] = *(const bf16x8*)&Ah[ar * 32 + quad * 8];                  \
            afl[t] = *(const bf16x8*)&Al[ar * 32 + quad * 8];                  \
            bfh[t] = *(const bf16x8*)&Bh[br * 32 + quad * 8];                  \
            bfl[t] = *(const bf16x8*)&Bl[br * 32 + quad * 8];                  \
        }                                                                      \
        _Pragma("unroll") for (int i = 0; i < 4; ++i)                          \
        _Pragma("unroll") for (int j = 0; j < 4; ++j) {                        \
            acc[i][j] = __builtin_amdgcn_mfma_f32_16x16x32_bf16(               \
                afh[i], bfh[j], acc[i][j], 0, 0, 0);                           \
            acc[i][j] = __builtin_amdgcn_mfma_f32_16x16x32_bf16(               \
                afh[i], bfl[j], acc[i][j], 0, 0, 0);                           \
            acc[i][j] = __builtin_amdgcn_mfma_f32_16x16x32_bf16(               \
                afl[i], bfh[j], acc[i][j], 0, 0, 0);                           \
        }                                                                      \
    } while (0)

__global__ __launch_bounds__(256) void gemm_mfma(
    const unsigned short* __restrict__ Xh, const unsigned short* __restrict__ Xl,
    const unsigned short* __restrict__ Wh, const unsigned short* __restrict__ Wl,
    const float* __restrict__ bias, const unsigned short* __restrict__ xah,
    const unsigned short* __restrict__ Bch, const unsigned short* __restrict__ Bcl,
    float* __restrict__ Cf, unsigned short* __restrict__ Ch, float alpha)
{
    __shared__ unsigned short Ah[128 * 32];
    __shared__ unsigned short Al[128 * 32];
    __shared__ unsigned short Bh[128 * 32];
    __shared__ unsigned short Bl[128 * 32];

    const int tid = threadIdx.x;
    const int m0 = blockIdx.y * 128;
    const int n0 = blockIdx.x * 128;
    const int lane = tid & 63;
    const int w = tid >> 6;
    const int wm = (w >> 1) * 64;
    const int wn = (w & 1) * 64;
    const int l16 = lane & 15;
    const int quad = lane >> 4;

    f32x4 acc[4][4];
#pragma unroll
    for (int i = 0; i < 4; ++i)
#pragma unroll
        for (int j = 0; j < 4; ++j) acc[i][j] = (f32x4){0.f, 0.f, 0.f, 0.f};

    const int srow = tid >> 2;
    const int scol = (tid & 3) * 8;
    const int lbase = (tid & 192) * 8;
    const size_t xr0 = (size_t)(m0 + srow) * DD + scol;
    const size_t xr1 = (size_t)(m0 + srow + 64) * DD + scol;
    const size_t wr0 = (size_t)(n0 + srow) * DD + scol;
    const size_t wr1 = (size_t)(n0 + srow + 64) * DD + scol;

#pragma unroll 1
    for (int kt = 0; kt < 32; ++kt) {
        const int k0 = kt * 32;
        gl_lds16(Xh + xr0 + k0, &Ah[lbase]);
        gl_lds16(Xh + xr1 + k0, &Ah[2048 + lbase]);
        gl_lds16(Xl + xr0 + k0, &Al[lbase]);
        gl_lds16(Xl + xr1 + k0, &Al[2048 + lbase]);
        gl_lds16(Wh + wr0 + k0, &Bh[lbase]);
        gl_lds16(Wh + wr1 + k0, &Bh[2048 + lbase]);
        gl_lds16(Wl + wr0 + k0, &Bl[lbase]);
        gl_lds16(Wl + wr1 + k0, &Bl[2048 + lbase]);
        __syncthreads();
        COMPUTE_CHUNK();
        __syncthreads();
    }

    // ---- LoRA expert tail: ONE masked K=32 chunk per batch in this m-tile
    {
        int m_hi = m0 + 127;
        if (m_hi >= MTOT) m_hi = MTOT - 1;
        const int b_first = m0 / SS;
        const int b_last = m_hi / SS;
        const int r = tid >> 1;
        const int c = (tid & 1) * 16;
        const uint4 z = make_uint4(0, 0, 0, 0);
#pragma unroll 1
        for (int bp = b_first; bp <= b_last; ++bp) {
            const int gm = m0 + r;
            const bool va = (gm < MTOT) && (gm / SS == bp);
            uint4 avh0 = z, avh1 = z;
            if (va) {
                avh0 = *(const uint4*)&xah[(size_t)gm * 32 + c];
                avh1 = *(const uint4*)&xah[(size_t)gm * 32 + c + 8];
            }
            const int gn = n0 + r;
            const size_t bo = ((size_t)bp * DD + gn) * 32 + c;
            uint4 bvh0 = *(const uint4*)&Bch[bo];
            uint4 bvh1 = *(const uint4*)&Bch[bo + 8];
            uint4 bvl0 = *(const uint4*)&Bcl[bo];
            uint4 bvl1 = *(const uint4*)&Bcl[bo + 8];
            __syncthreads();
            *(uint4*)&Ah[r * 32 + c] = avh0;
            *(uint4*)&Ah[r * 32 + c + 8] = avh1;
            *(uint4*)&Al[r * 32 + c] = z;
            *(uint4*)&Al[r * 32 + c + 8] = z;
            *(uint4*)&Bh[r * 32 + c] = bvh0;
            *(uint4*)&Bh[r * 32 + c + 8] = bvh1;
            *(uint4*)&Bl[r * 32 + c] = bvl0;
            *(uint4*)&Bl[r * 32 + c + 8] = bvl1;
            __syncthreads();
            COMPUTE_CHUNK();
            __syncthreads();
        }
    }

    // ---- epilogue: + bias, * alpha. C layout: col=lane&15, row=quad*4+reg
#pragma unroll
    for (int j = 0; j < 4; ++j) {
        const int n = n0 + wn + j * 16 + l16;
        const float bv = bias[n];
#pragma unroll
        for (int i = 0; i < 4; ++i) {
            const int mb = m0 + wm + i * 16 + quad * 4;
#pragma unroll
            for (int rg = 0; rg < 4; ++rg) {
                const int m = mb + rg;
                if (m < MTOT) {
                    float val = alpha * (acc[i][j][rg] + bv);
                    size_t off = (size_t)m * DD + n;
                    if (Cf) Cf[off] = val;
                    else Ch[off] = bf16h(val);
                }
            }
        }
    }
}

// ---------------------------------------------------------------------------
// attn_mfma: softmax(qh kh^T) vh per (b,h,32-q-rows). bf16 MFMA both passes.
// Writes split bf16 Xh/Xl (consumed by o-GEMM and xa_o). grid (9, 16, 32).
// ---------------------------------------------------------------------------
__global__ __launch_bounds__(256) void attn_mfma(
    const unsigned short* __restrict__ qh, const unsigned short* __restrict__ kh,
    const unsigned short* __restrict__ vh, unsigned short* __restrict__ Xh,
    unsigned short* __restrict__ Xl)
{
    __shared__ unsigned short Qs[32 * 64];
    __shared__ unsigned short Ks[32 * 64];
    __shared__ unsigned short Vt[64 * 34];
    __shared__ float Ls[32 * 296];
    __shared__ unsigned short Ps[32 * 296];

    const int tid = threadIdx.x;
    const int b = blockIdx.z, h = blockIdx.y;
    const int s0 = blockIdx.x * 32;
    const int cb = h * HDIM;
    const int lane = tid & 63;
    const int w = tid >> 6;
    const int l16 = lane & 15;
    const int quad = lane >> 4;
    const int mrow = (w & 1) * 16;
    const int ncol = (w >> 1) * 16;
    const int sr = tid >> 3;
    const int sc8 = (tid & 7) * 8;

    // stage Q (32x64), clamp rows
    {
        int sg = s0 + sr;
        if (sg > SS - 1) sg = SS - 1;
        gl_lds16(qh + (size_t)(b * SS + sg) * DD + cb + sc8,
                 &Qs[(tid & 192) * 8]);
    }

    // ---- pass 1: logits ----
#pragma unroll 1
    for (int tt = 0; tt < 9; ++tt) {
        const int t0 = tt * 32;
        {
            int tg = t0 + sr;
            if (tg > SS - 1) tg = SS - 1;
            gl_lds16(kh + (size_t)(b * SS + tg) * DD + cb + sc8,
                     &Ks[(tid & 192) * 8]);
        }
        __syncthreads();
        f32x4 acc = (f32x4){0.f, 0.f, 0.f, 0.f};
#pragma unroll
        for (int kc = 0; kc < 2; ++kc) {
            bf16x8 af =
                *(const bf16x8*)&Qs[(mrow + l16) * 64 + kc * 32 + quad * 8];
            bf16x8 bf =
                *(const bf16x8*)&Ks[(ncol + l16) * 64 + kc * 32 + quad * 8];
            acc = __builtin_amdgcn_mfma_f32_16x16x32_bf16(af, bf, acc, 0, 0, 0);
        }
#pragma unroll
        for (int rg = 0; rg < 4; ++rg)
            Ls[(mrow + quad * 4 + rg) * 296 + t0 + ncol + l16] = acc[rg];
        __syncthreads();
    }

    // ---- softmax (8 lanes per row), write bf16 probs to Ps ----
    {
        const int r = tid >> 3, g = tid & 7;
        float mx = -1e30f;
        for (int t = g; t < SS; t += 8) mx = fmaxf(mx, Ls[r * 296 + t]);
        mx = fmaxf(mx, __shfl_xor(mx, 1, 8));
        mx = fmaxf(mx, __shfl_xor(mx, 2, 8));
        mx = fmaxf(mx, __shfl_xor(mx, 4, 8));
        float sum = 0.f;
        for (int t = g; t < SS; t += 8) {
            float p = __expf(Ls[r * 296 + t] - mx);
            Ls[r * 296 + t] = p;
            sum += p;
        }
        sum += __shfl_xor(sum, 1, 8);
        sum += __shfl_xor(sum, 2, 8);
        sum += __shfl_xor(sum, 4, 8);
        const float inv = 1.f / sum;
        for (int t = g; t < SS; t += 8)
            Ps[r * 296 + t] = bf16h(Ls[r * 296 + t] * inv);
        for (int t = SS + g; t < 288; t += 8) Ps[r * 296 + t] = 0;
    }

    // ---- pass 2: P @ V (V transposed in LDS via VGPR) ----
    const int dcol = (w >> 1) * 32;
    f32x4 oacc[2];
    oacc[0] = (f32x4){0.f, 0.f, 0.f, 0.f};
    oacc[1] = (f32x4){0.f, 0.f, 0.f, 0.f};
#pragma unroll 1
    for (int tt = 0; tt < 9; ++tt) {
        const int t0 = tt * 32;
        int tg = t0 + sr;
        if (tg > SS - 1) tg = SS - 1;
        uint4 vv = *(const uint4*)&vh[(size_t)(b * SS + tg) * DD + cb + sc8];
        unsigned short vs[8];
        *(uint4*)vs = vv;
        __syncthreads(); // prior tile's Vt/Ps reads complete
#pragma unroll
        for (int u = 0; u < 8; ++u) Vt[(sc8 + u) * 34 + sr] = vs[u];
        __syncthreads();
        bf16x8 pf = *(const bf16x8*)&Ps[(mrow + l16) * 296 + t0 + quad * 8];
#pragma unroll
        for (int dt = 0; dt < 2; ++dt) {
            const unsigned short* vp =
                &Vt[(dcol + dt * 16 + l16) * 34 + quad * 8];
            bf16x8 bv;
            ((unsigned int*)&bv)[0] = *(const unsigned int*)(vp + 0);
            ((unsigned int*)&bv)[1] = *(const unsigned int*)(vp + 2);
            ((unsigned int*)&bv)[2] = *(const unsigned int*)(vp + 4);
            ((unsigned int*)&bv)[3] = *(const unsigned int*)(vp + 6);
            oacc[dt] =
                __builtin_amdgcn_mfma_f32_16x16x32_bf16(pf, bv, oacc[dt], 0, 0, 0);
        }
    }

    // ---- epilogue: split-bf16 store ----
#pragma unroll
    for (int dt = 0; dt < 2; ++dt)
#pragma unroll
        for (int rg = 0; rg < 4; ++rg) {
            int srow = s0 + mrow + quad * 4 + rg;
            if (srow < SS) {
                size_t off =
                    (size_t)(b * SS + srow) * DD + cb + dcol + dt * 16 + l16;
                unsigned short hh, ll;
                split1(oacc[dt][rg], hh, ll);
                Xh[off] = hh;
                Xl[off] = ll;
            }
        }
}

// ---------------------------------------------------------------------------
extern "C" void kernel_launch(void* const* d_in, const int* in_sizes, int n_in,
                              void* d_out, int out_size, void* d_ws,
                              size_t ws_size, hipStream_t stream)
{
    const float* hidden = (const float*)d_in[0];
    const int* tki = (const int*)d_in[1];
    const float* tkg = (const float*)d_in[2];
    const float* wq = (const float*)d_in[3];
    const float* Aq = (const float*)d_in[4];
    const float* Bq = (const float*)d_in[5];
    const float* bq = (const float*)d_in[6];
    const float* wk = (const float*)d_in[7];
    const float* Ak = (const float*)d_in[8];
    const float* Bk = (const float*)d_in[9];
    const float* bkb = (const float*)d_in[10];
    const float* wv = (const float*)d_in[11];
    const float* Av = (const float*)d_in[12];
    const float* Bv = (const float*)d_in[13];
    const float* bvb = (const float*)d_in[14];
    const float* wo = (const float*)d_in[15];
    const float* Ao = (const float*)d_in[16];
    const float* Bo = (const float*)d_in[17];
    const float* bob = (const float*)d_in[18];
    float* out = (float*)d_out;

    // ---- workspace carve-up (bytes), ~78 MB ----
    char* ws = (char*)d_ws;
    const size_t MD_H = (size_t)MTOT * DD * 2;   // 16.84 MB
    const size_t MPD_H = (size_t)MPAD * DD * 2;  // 17.04 MB
    const size_t W_H = (size_t)DD * DD * 2;      // 2.1 MB
    const size_t BC_H = (size_t)BB * DD * 32 * 2;
    const size_t XA_H = (size_t)MTOT * 32 * 2;   // 0.53 MB

    unsigned short* qh = (unsigned short*)ws;  ws += MD_H;
    unsigned short* vh = (unsigned short*)ws;  ws += MD_H;
    unsigned short* Xh = (unsigned short*)ws;  ws += MPD_H;
    unsigned short* Xl = (unsigned short*)ws;  ws += MPD_H;
    unsigned short* Wh = (unsigned short*)ws;  ws += W_H;
    unsigned short* Wl = (unsigned short*)ws;  ws += W_H;
    unsigned short* Bch = (unsigned short*)ws; ws += BC_H;
    unsigned short* Bcl = (unsigned short*)ws; ws += BC_H;
    unsigned short* xhq = (unsigned short*)ws; ws += XA_H;
    unsigned short* xhk = (unsigned short*)ws; ws += XA_H;
    unsigned short* xhv = (unsigned short*)ws; ws += XA_H;
    unsigned short* xho = (unsigned short*)ws; ws += XA_H;
    unsigned short* kh = (unsigned short*)d_out; // parked; dead before o-GEMM

    const long NX_V = (long)MTOT * DD, NX_T = (long)MPAD * DD;
    const long NW = (long)DD * DD;

    dim3 blk(256);
    dim3 gsX(NX_T / 1024);
    dim3 gsW(NW / 1024);
    dim3 gbc(128, BB);
    dim3 gxa3(5, BB * KEXP);
    dim3 gxa1(5, BB);
    dim3 ggemm(8, 65);
    dim3 gattn(9, HH, BB);

    // X -> hi/lo (padded)
    split_kernel<<<gsX, blk, 0, stream>>>(hidden, Xh, Xl, NX_V, NX_T);
    // xa for q,k,v (shares X reads)
    xa_qkv<<<gxa3, blk, 0, stream>>>(hidden, Aq, Ak, Av, tki, tkg, xhq, xhk,
                                     xhv);
    // Q
    split_kernel<<<gsW, blk, 0, stream>>>(wq, Wh, Wl, NW, NW);
    bcat_kernel<<<gbc, blk, 0, stream>>>(Bq, tki, Bch, Bcl);
    gemm_mfma<<<ggemm, blk, 0, stream>>>(Xh, Xl, Wh, Wl, bq, xhq, Bch, Bcl,
                                         nullptr, qh, 0.125f);
    // K
    split_kernel<<<gsW, blk, 0, stream>>>(wk, Wh, Wl, NW, NW);
    bcat_kernel<<<gbc, blk, 0, stream>>>(Bk, tki, Bch, Bcl);
    gemm_mfma<<<ggemm, blk, 0, stream>>>(Xh, Xl, Wh, Wl, bkb, xhk, Bch, Bcl,
                                         nullptr, kh, 1.0f);
    // V
    split_kernel<<<gsW, blk, 0, stream>>>(wv, Wh, Wl, NW, NW);
    bcat_kernel<<<gbc, blk, 0, stream>>>(Bv, tki, Bch, Bcl);
    gemm_mfma<<<ggemm, blk, 0, stream>>>(Xh, Xl, Wh, Wl, bvb, xhv, Bch, Bcl,
                                         nullptr, vh, 1.0f);

    // attention: overwrites Xh/Xl with split attn output
    attn_mfma<<<gattn, blk, 0, stream>>>(qh, kh, vh, Xh, Xl);

    // O projection
    xa_o<<<gxa1, blk, 0, stream>>>(Xh, Xl, Ao, tki, tkg, xho);
    split_kernel<<<gsW, blk, 0, stream>>>(wo, Wh, Wl, NW, NW);
    bcat_kernel<<<gbc, blk, 0, stream>>>(Bo, tki, Bch, Bcl);
    gemm_mfma<<<ggemm, blk, 0, stream>>>(Xh, Xl, Wh, Wl, bob, xho, Bch, Bcl,
                                         out, nullptr, 1.0f);
}

// Round 5
// 585.574 us; speedup vs baseline: 4.6212x; 1.3971x over previous
//
#include <hip/hip_runtime.h>

// ViTMoEAttention: B=32,S=257,D=1024,H=16,HD=64,E=8,R=16,K=2
// Round 5:
//  - GEMMs: split-fp16 (xh+xl) x fp16 W, TWO MFMA products (was bf16 x3).
//    XOR-swizzled LDS (key (row>>1)&3) kills the 8-way ds_read_b128 conflict.
//  - attn_v3: one block per (b,h), K + V^T resident in LDS (123 KB),
//    5 q-tiles of 64 rows, register softmax (shfl + tiny LDS combine),
//    fp16 MFMA for QK^T and PV. 5 barriers/q-tile.
//  - All attention-side tensors fp16 (q,k,v,P); attn emits fp16 split hi/lo.

#define BB 32
#define SS 257
#define DD 1024
#define HH 16
#define HDIM 64
#define EE 8
#define RR 16
#define KEXP 2
#define MTOT (BB * SS)   // 8224
#define MPAD 8320        // 65 * 128

typedef __attribute__((ext_vector_type(8))) _Float16 f16x8;
typedef __attribute__((ext_vector_type(4))) float f32x4;

static __device__ __forceinline__ float4 ld4(const float* p) {
    return *(const float4*)p;
}

static __device__ __forceinline__ unsigned short f16bits(_Float16 v) {
    union { _Float16 f; unsigned short u; } cv; cv.f = v; return cv.u;
}
static __device__ __forceinline__ _Float16 bits2h(unsigned short u) {
    union { unsigned short u; _Float16 f; } cv; cv.u = u; return cv.f;
}
// split fp32 -> fp16 hi + fp16 lo (x ~= hi+lo exact to ~2^-22)
static __device__ __forceinline__ void split1h(float x, unsigned short& h,
                                               unsigned short& l) {
    _Float16 hh = (_Float16)x;
    _Float16 ll = (_Float16)(x - (float)hh);
    h = f16bits(hh);
    l = f16bits(ll);
}

static __device__ __forceinline__ void gl_lds16(const unsigned short* g,
                                                unsigned short* l) {
    __builtin_amdgcn_global_load_lds(
        (const __attribute__((address_space(1))) unsigned int*)g,
        (__attribute__((address_space(3))) unsigned int*)l, 16, 0, 0);
}

// ---------------------------------------------------------------------------
// split16_kernel: fp32 src -> fp16 hi/lo; pads [nvalid, ntotal) with 0.
// ---------------------------------------------------------------------------
__global__ __launch_bounds__(256) void split16_kernel(
    const float* __restrict__ src, unsigned short* __restrict__ h,
    unsigned short* __restrict__ l, long nvalid, long ntotal)
{
    long i = ((long)blockIdx.x * 256 + threadIdx.x) * 4;
    if (i >= ntotal) return;
    float4 v = (i < nvalid) ? ld4(&src[i]) : make_float4(0.f, 0.f, 0.f, 0.f);
    ushort4 hv, lv;
    split1h(v.x, hv.x, lv.x);
    split1h(v.y, hv.y, lv.y);
    split1h(v.z, hv.z, lv.z);
    split1h(v.w, hv.w, lv.w);
    *(ushort4*)&h[i] = hv;
    if (l) *(ushort4*)&l[i] = lv;
}

// ---------------------------------------------------------------------------
// Bcat[b][n][ke*16+r] = Ball[idx[b][ke]][n][r]  (fp16)
// ---------------------------------------------------------------------------
__global__ __launch_bounds__(256) void bcat_kernel(
    const float* __restrict__ Ball, const int* __restrict__ idx,
    unsigned short* __restrict__ h)
{
    int b = blockIdx.y;
    int i = blockIdx.x * 256 + threadIdx.x; // 0..32767
    int n = i >> 5, kk = i & 31;
    int ke = kk >> 4, r = kk & 15;
    int e = idx[b * KEXP + ke];
    float x = Ball[((size_t)e * DD + n) * RR + r];
    h[((size_t)b * DD + n) * (KEXP * RR) + kk] = f16bits((_Float16)x);
}

// ---------------------------------------------------------------------------
// xa_qkv: xa_p[m][ke*16+r] = g * sum_d X[m][d]*A_p[e][r][d], p in {q,k,v}
// sharing X reads. fp32 VALU, fp16 out. grid (5, 64).
// ---------------------------------------------------------------------------
__global__ __launch_bounds__(256) void xa_qkv(
    const float* __restrict__ X, const float* __restrict__ Aq,
    const float* __restrict__ Ak, const float* __restrict__ Av,
    const int* __restrict__ idx, const float* __restrict__ gates,
    unsigned short* __restrict__ xq, unsigned short* __restrict__ xk,
    unsigned short* __restrict__ xv)
{
    __shared__ float Xs[64][68];
    __shared__ float As[48][68];
    const int tid = threadIdx.x;
    const int bk = blockIdx.y;
    const int b = bk >> 1, ke = bk & 1;
    const int s0 = blockIdx.x * 64;
    const int e = idx[b * 2 + ke];
    const float g = gates[b * 2 + ke];
    const int tx = tid & 15, ty = tid >> 4;
    const int c4 = tx * 4;

    float acc[4][3];
#pragma unroll
    for (int a = 0; a < 4; ++a)
#pragma unroll
        for (int p = 0; p < 3; ++p) acc[a][p] = 0.f;

#pragma unroll 1
    for (int kt = 0; kt < 16; ++kt) {
        const int k0 = kt * 64;
        __syncthreads();
#pragma unroll
        for (int p = 0; p < 4; ++p) {
            int row = ty + p * 16;
            int sg = s0 + row;
            if (sg > SS - 1) sg = SS - 1;
            *(float4*)&Xs[row][c4] =
                ld4(&X[(size_t)(b * SS + sg) * DD + k0 + c4]);
        }
#pragma unroll
        for (int p = 0; p < 3; ++p) {
            const float* Ap = (p == 0) ? Aq : (p == 1) ? Ak : Av;
            *(float4*)&As[p * 16 + ty][c4] =
                ld4(&Ap[(size_t)(e * RR + ty) * DD + k0 + c4]);
        }
        __syncthreads();
#pragma unroll 4
        for (int k4 = 0; k4 < 16; ++k4) {
            float4 xr[4], ar[3];
#pragma unroll
            for (int a = 0; a < 4; ++a)
                xr[a] = *(float4*)&Xs[ty + 16 * a][k4 * 4];
#pragma unroll
            for (int p = 0; p < 3; ++p)
                ar[p] = *(float4*)&As[tx + 16 * p][k4 * 4];
#pragma unroll
            for (int a = 0; a < 4; ++a)
#pragma unroll
                for (int p = 0; p < 3; ++p) {
                    acc[a][p] = fmaf(xr[a].x, ar[p].x, acc[a][p]);
                    acc[a][p] = fmaf(xr[a].y, ar[p].y, acc[a][p]);
                    acc[a][p] = fmaf(xr[a].z, ar[p].z, acc[a][p]);
                    acc[a][p] = fmaf(xr[a].w, ar[p].w, acc[a][p]);
                }
        }
    }
#pragma unroll
    for (int a = 0; a < 4; ++a) {
        int sg = s0 + ty + 16 * a;
        if (sg < SS) {
            size_t o = (size_t)(b * SS + sg) * 32 + ke * RR + tx;
            xq[o] = f16bits((_Float16)(g * acc[a][0]));
            xk[o] = f16bits((_Float16)(g * acc[a][1]));
            xv[o] = f16bits((_Float16)(g * acc[a][2]));
        }
    }
}

// ---------------------------------------------------------------------------
// xa_o: X reconstructed from fp16 Xh+Xl (attn output); both ke. grid (5,32).
// ---------------------------------------------------------------------------
__global__ __launch_bounds__(256) void xa_o(
    const unsigned short* __restrict__ Xhb,
    const unsigned short* __restrict__ Xlb, const float* __restrict__ Ao,
    const int* __restrict__ idx, const float* __restrict__ gates,
    unsigned short* __restrict__ xo)
{
    __shared__ float Xs[64][68];
    __shared__ float As[32][68];
    const int tid = threadIdx.x;
    const int b = blockIdx.y;
    const int s0 = blockIdx.x * 64;
    const int e0 = idx[b * 2 + 0], e1 = idx[b * 2 + 1];
    const float g0 = gates[b * 2 + 0], g1 = gates[b * 2 + 1];
    const int tx = tid & 15, ty = tid >> 4;
    const int c4 = tx * 4;

    float acc[4][2];
#pragma unroll
    for (int a = 0; a < 4; ++a) { acc[a][0] = 0.f; acc[a][1] = 0.f; }

#pragma unroll 1
    for (int kt = 0; kt < 16; ++kt) {
        const int k0 = kt * 64;
        __syncthreads();
#pragma unroll
        for (int p = 0; p < 4; ++p) {
            int row = ty + p * 16;
            int sg = s0 + row;
            if (sg > SS - 1) sg = SS - 1;
            size_t off = (size_t)(b * SS + sg) * DD + k0 + c4;
            ushort4 hv = *(const ushort4*)&Xhb[off];
            ushort4 lv = *(const ushort4*)&Xlb[off];
            float4 xf;
            xf.x = (float)bits2h(hv.x) + (float)bits2h(lv.x);
            xf.y = (float)bits2h(hv.y) + (float)bits2h(lv.y);
            xf.z = (float)bits2h(hv.z) + (float)bits2h(lv.z);
            xf.w = (float)bits2h(hv.w) + (float)bits2h(lv.w);
            *(float4*)&Xs[row][c4] = xf;
        }
#pragma unroll
        for (int p = 0; p < 2; ++p) {
            int e = (p == 0) ? e0 : e1;
            *(float4*)&As[p * 16 + ty][c4] =
                ld4(&Ao[(size_t)(e * RR + ty) * DD + k0 + c4]);
        }
        __syncthreads();
#pragma unroll 4
        for (int k4 = 0; k4 < 16; ++k4) {
            float4 xr[4], ar[2];
#pragma unroll
            for (int a = 0; a < 4; ++a)
                xr[a] = *(float4*)&Xs[ty + 16 * a][k4 * 4];
#pragma unroll
            for (int p = 0; p < 2; ++p)
                ar[p] = *(float4*)&As[tx + 16 * p][k4 * 4];
#pragma unroll
            for (int a = 0; a < 4; ++a)
#pragma unroll
                for (int p = 0; p < 2; ++p) {
                    acc[a][p] = fmaf(xr[a].x, ar[p].x, acc[a][p]);
                    acc[a][p] = fmaf(xr[a].y, ar[p].y, acc[a][p]);
                    acc[a][p] = fmaf(xr[a].z, ar[p].z, acc[a][p]);
                    acc[a][p] = fmaf(xr[a].w, ar[p].w, acc[a][p]);
                }
        }
    }
#pragma unroll
    for (int a = 0; a < 4; ++a) {
        int sg = s0 + ty + 16 * a;
        if (sg < SS) {
            size_t o = (size_t)(b * SS + sg) * 32;
            xo[o + tx] = f16bits((_Float16)(g0 * acc[a][0]));
            xo[o + 16 + tx] = f16bits((_Float16)(g1 * acc[a][1]));
        }
    }
}

// ---------------------------------------------------------------------------
// MFMA GEMM (fp16): C = alpha*((Xh+Xl) W^T + xa Bcat^T + bias)
// 128x128 tile, BK=32, XOR-swizzled LDS (key (row>>1)&3). grid (8,65).
// ---------------------------------------------------------------------------
#define COMPUTE_CHUNK()                                                        \
    do {                                                                       \
        f16x8 afh[4], afl[4], bfh[4];                                          \
        const int sb = (quad ^ ((l16 >> 1) & 3)) * 8;                          \
        _Pragma("unroll") for (int t = 0; t < 4; ++t) {                        \
            int ar = wm + t * 16 + l16;                                        \
            int br = wn + t * 16 + l16;                                        \
            afh[t] = *(const f16x8*)&Ah[ar * 32 + sb];                         \
            afl[t] = *(const f16x8*)&Al[ar * 32 + sb];                         \
            bfh[t] = *(const f16x8*)&Bh[br * 32 + sb];                         \
        }                                                                      \
        _Pragma("unroll") for (int i = 0; i < 4; ++i)                          \
        _Pragma("unroll") for (int j = 0; j < 4; ++j) {                        \
            acc[i][j] = __builtin_amdgcn_mfma_f32_16x16x32_f16(                \
                afh[i], bfh[j], acc[i][j], 0, 0, 0);                           \
            acc[i][j] = __builtin_amdgcn_mfma_f32_16x16x32_f16(                \
                afl[i], bfh[j], acc[i][j], 0, 0, 0);                           \
        }                                                                      \
    } while (0)

__global__ __launch_bounds__(256) void gemm_mfma(
    const unsigned short* __restrict__ Xh, const unsigned short* __restrict__ Xl,
    const unsigned short* __restrict__ Wh, const float* __restrict__ bias,
    const unsigned short* __restrict__ xah, const unsigned short* __restrict__ Bch,
    float* __restrict__ Cf, unsigned short* __restrict__ Ch, float alpha)
{
    __shared__ unsigned short Ah[128 * 32];
    __shared__ unsigned short Al[128 * 32];
    __shared__ unsigned short Bh[128 * 32];

    const int tid = threadIdx.x;
    const int m0 = blockIdx.y * 128;
    const int n0 = blockIdx.x * 128;
    const int lane = tid & 63;
    const int w = tid >> 6;
    const int wm = (w >> 1) * 64;
    const int wn = (w & 1) * 64;
    const int l16 = lane & 15;
    const int quad = lane >> 4;

    f32x4 acc[4][4];
#pragma unroll
    for (int i = 0; i < 4; ++i)
#pragma unroll
        for (int j = 0; j < 4; ++j) acc[i][j] = (f32x4){0.f, 0.f, 0.f, 0.f};

    // staging: per call 256 thr x 16B = 64 rows x 64B; swizzled source group
    const int srow = tid >> 2;
    const int scol = (((tid & 3) ^ ((tid >> 3) & 3))) * 8; // swizzled k-group
    const int lbase = (tid & 192) * 8;
    const size_t xr0 = (size_t)(m0 + srow) * DD + scol;
    const size_t xr1 = (size_t)(m0 + srow + 64) * DD + scol;
    const size_t wr0 = (size_t)(n0 + srow) * DD + scol;
    const size_t wr1 = (size_t)(n0 + srow + 64) * DD + scol;

#pragma unroll 1
    for (int kt = 0; kt < 32; ++kt) {
        const int k0 = kt * 32;
        gl_lds16(Xh + xr0 + k0, &Ah[lbase]);
        gl_lds16(Xh + xr1 + k0, &Ah[2048 + lbase]);
        gl_lds16(Xl + xr0 + k0, &Al[lbase]);
        gl_lds16(Xl + xr1 + k0, &Al[2048 + lbase]);
        gl_lds16(Wh + wr0 + k0, &Bh[lbase]);
        gl_lds16(Wh + wr1 + k0, &Bh[2048 + lbase]);
        __syncthreads();
        COMPUTE_CHUNK();
        __syncthreads();
    }

    // ---- LoRA tail: one masked K=32 chunk per batch index in this m-tile
    {
        int m_hi = m0 + 127;
        if (m_hi >= MTOT) m_hi = MTOT - 1;
        const int b_first = m0 / SS;
        const int b_last = m_hi / SS;
        const int r = tid >> 1;
        const int key = (r >> 1) & 3;
        const int b0 = (tid & 1) * 2;
        const uint4 z = make_uint4(0, 0, 0, 0);
#pragma unroll 1
        for (int bp = b_first; bp <= b_last; ++bp) {
            const int gm = m0 + r;
            const bool va = (gm < MTOT) && (gm / SS == bp);
            uint4 av0 = z, av1 = z;
            if (va) {
                av0 = *(const uint4*)&xah[(size_t)gm * 32 + (b0 ^ key) * 8];
                av1 = *(const uint4*)&xah[(size_t)gm * 32 + ((b0 + 1) ^ key) * 8];
            }
            const int gn = n0 + r;
            const size_t bo = ((size_t)bp * DD + gn) * 32;
            uint4 bv0 = *(const uint4*)&Bch[bo + (b0 ^ key) * 8];
            uint4 bv1 = *(const uint4*)&Bch[bo + ((b0 + 1) ^ key) * 8];
            __syncthreads();
            *(uint4*)&Ah[r * 32 + b0 * 8] = av0;
            *(uint4*)&Ah[r * 32 + (b0 + 1) * 8] = av1;
            *(uint4*)&Al[r * 32 + b0 * 8] = z;
            *(uint4*)&Al[r * 32 + (b0 + 1) * 8] = z;
            *(uint4*)&Bh[r * 32 + b0 * 8] = bv0;
            *(uint4*)&Bh[r * 32 + (b0 + 1) * 8] = bv1;
            __syncthreads();
            COMPUTE_CHUNK();
            __syncthreads();
        }
    }

    // ---- epilogue: C layout col=lane&15, row=quad*4+reg
#pragma unroll
    for (int j = 0; j < 4; ++j) {
        const int n = n0 + wn + j * 16 + l16;
        const float bv = bias[n];
#pragma unroll
        for (int i = 0; i < 4; ++i) {
            const int mb = m0 + wm + i * 16 + quad * 4;
#pragma unroll
            for (int rg = 0; rg < 4; ++rg) {
                const int m = mb + rg;
                if (m < MTOT) {
                    float val = alpha * (acc[i][j][rg] + bv);
                    size_t off = (size_t)m * DD + n;
                    if (Cf) Cf[off] = val;
                    else Ch[off] = f16bits((_Float16)val);
                }
            }
        }
    }
}

// ---------------------------------------------------------------------------
// attn_v3: one block per (b,h). K + V^T resident in LDS; 5 q-tiles of 64;
// register softmax; fp16 MFMA. 512 threads (8 waves: rowgrp=w&3, colhalf=w>>2).
// ---------------------------------------------------------------------------
__global__ __launch_bounds__(512, 1) void attn_v3(
    const unsigned short* __restrict__ qh, const unsigned short* __restrict__ kh,
    const unsigned short* __restrict__ vh, unsigned short* __restrict__ Xh,
    unsigned short* __restrict__ Xl)
{
    __shared__ unsigned short Ks[288 * 64]; // rows 257+ zero; XOR-swizzled
    __shared__ unsigned short Vt[64 * 312]; // V^T, stride 312, t>=257 zero
    __shared__ unsigned short Qs[64 * 64];  // XOR-swizzled
    __shared__ unsigned short Ps[64 * 312]; // probs fp16, stride 312
    __shared__ float sredm[2][64];
    __shared__ float sreds[2][64];

    const int tid = threadIdx.x;
    const int h = blockIdx.x, b = blockIdx.y;
    const int cb = h * HDIM;
    const int lane = tid & 63;
    const int w = tid >> 6;
    const int r0 = (w & 3) * 16; // q-row group within 64-row tile
    const int ch = w >> 2;       // col half (144 cols each, padded to 288)
    const int l16 = lane & 15;
    const int quad = lane >> 4;

    // ---- stage K rows 0..255 (gl_lds16, swizzled source col-group) ----
    const size_t kbase = (size_t)(b * SS) * DD + cb;
    {
        const int rr = w * 8 + (lane >> 3);
        const int cg = ((lane & 7) ^ (rr & 7)) * 8;
#pragma unroll
        for (int c = 0; c < 4; ++c)
            gl_lds16(kh + kbase + (size_t)(c * 64 + rr) * DD + cg,
                     &Ks[(c * 64 + w * 8) * 64]);
    }
    // rows 256..287: row 256 real (swizzle key 256&7=0 -> identity), rest 0
    if (tid < 256) {
        uint4 z = make_uint4(0, 0, 0, 0);
        if (tid < 8) z = *(const uint4*)&kh[kbase + (size_t)256 * DD + tid * 8];
        *(uint4*)&Ks[256 * 64 + tid * 8] = z;
    }
    // memset Vt (64*312 = 19968 ushorts = 2496 uint4)
    {
        uint4 z = make_uint4(0, 0, 0, 0);
        for (int i = tid; i < 2496; i += 512) *(uint4*)&Vt[i * 8] = z;
    }
    __syncthreads();
    // fill V^T: thread t reads its V row, scatters 64 scalars
    if (tid < SS) {
        const size_t vbase = (size_t)(b * SS + tid) * DD + cb;
#pragma unroll
        for (int dc = 0; dc < 8; ++dc) {
            uint4 vv = *(const uint4*)&vh[vbase + dc * 8];
            unsigned short vs[8];
            *(uint4*)vs = vv;
#pragma unroll
            for (int u = 0; u < 8; ++u) Vt[(dc * 8 + u) * 312 + tid] = vs[u];
        }
    }

    // ---- q-tile loop ----
#pragma unroll 1
    for (int qt = 0; qt < 5; ++qt) {
        const int s0 = qt * 64;
        __syncthreads(); // Qs/Ps free from previous iter; Vt/Ks ready (iter 0)
        {
            int sg = s0 + (tid >> 3);
            if (sg > SS - 1) sg = SS - 1;
            const int cg = ((tid & 7) ^ ((tid >> 3) & 7)) * 8;
            gl_lds16(qh + (size_t)(b * SS + sg) * DD + cb + cg,
                     &Qs[(w * 8) * 64]);
        }
        __syncthreads(); // Qs ready

        // ---- QK^T ----
        f32x4 lac[9];
#pragma unroll
        for (int ct = 0; ct < 9; ++ct) lac[ct] = (f32x4){0.f, 0.f, 0.f, 0.f};
#pragma unroll
        for (int kc = 0; kc < 2; ++kc) {
            const int sb = ((kc * 4 + quad) ^ (l16 & 7)) * 8;
            f16x8 af = *(const f16x8*)&Qs[(r0 + l16) * 64 + sb];
#pragma unroll
            for (int ct = 0; ct < 9; ++ct) {
                const int c0 = ch * 144 + ct * 16;
                f16x8 bf = *(const f16x8*)&Ks[(c0 + l16) * 64 + sb];
                lac[ct] = __builtin_amdgcn_mfma_f32_16x16x32_f16(af, bf,
                                                                 lac[ct], 0, 0, 0);
            }
        }
        // mask pad cols (t>256)
#pragma unroll
        for (int ct = 0; ct < 9; ++ct) {
            const int t = ch * 144 + ct * 16 + l16;
            if (t > SS - 1) {
                lac[ct][0] = -1e30f; lac[ct][1] = -1e30f;
                lac[ct][2] = -1e30f; lac[ct][3] = -1e30f;
            }
        }
        // ---- register softmax (rows r0+quad*4+i) ----
        float mx[4] = {-1e30f, -1e30f, -1e30f, -1e30f};
#pragma unroll
        for (int ct = 0; ct < 9; ++ct)
#pragma unroll
            for (int i = 0; i < 4; ++i) mx[i] = fmaxf(mx[i], lac[ct][i]);
#pragma unroll
        for (int o = 1; o < 16; o <<= 1)
#pragma unroll
            for (int i = 0; i < 4; ++i)
                mx[i] = fmaxf(mx[i], __shfl_xor(mx[i], o, 16));
        if (l16 == 0)
#pragma unroll
            for (int i = 0; i < 4; ++i) sredm[ch][r0 + quad * 4 + i] = mx[i];
        __syncthreads();
#pragma unroll
        for (int i = 0; i < 4; ++i)
            mx[i] = fmaxf(mx[i], sredm[1 - ch][r0 + quad * 4 + i]);
        float sm[4] = {0.f, 0.f, 0.f, 0.f};
#pragma unroll
        for (int ct = 0; ct < 9; ++ct)
#pragma unroll
            for (int i = 0; i < 4; ++i) {
                float p = __expf(lac[ct][i] - mx[i]);
                lac[ct][i] = p;
                sm[i] += p;
            }
#pragma unroll
        for (int o = 1; o < 16; o <<= 1)
#pragma unroll
            for (int i = 0; i < 4; ++i) sm[i] += __shfl_xor(sm[i], o, 16);
        if (l16 == 0)
#pragma unroll
            for (int i = 0; i < 4; ++i) sreds[ch][r0 + quad * 4 + i] = sm[i];
        __syncthreads();
        float inv[4];
#pragma unroll
        for (int i = 0; i < 4; ++i)
            inv[i] = 1.f / (sm[i] + sreds[1 - ch][r0 + quad * 4 + i]);
        // write P (fp16)
#pragma unroll
        for (int ct = 0; ct < 9; ++ct) {
            const int col = ch * 144 + ct * 16 + l16;
#pragma unroll
            for (int i = 0; i < 4; ++i)
                Ps[(r0 + quad * 4 + i) * 312 + col] =
                    f16bits((_Float16)(lac[ct][i] * inv[i]));
        }
        __syncthreads(); // Ps ready

        // ---- P @ V (no barriers inside) ----
        f32x4 oacc[2];
        oacc[0] = (f32x4){0.f, 0.f, 0.f, 0.f};
        oacc[1] = (f32x4){0.f, 0.f, 0.f, 0.f};
#pragma unroll
        for (int tt = 0; tt < 9; ++tt) {
            const int t0 = tt * 32;
            f16x8 pf = *(const f16x8*)&Ps[(r0 + l16) * 312 + t0 + quad * 8];
#pragma unroll
            for (int dt = 0; dt < 2; ++dt) {
                f16x8 bv = *(const f16x8*)&Vt[(ch * 32 + dt * 16 + l16) * 312 +
                                              t0 + quad * 8];
                oacc[dt] = __builtin_amdgcn_mfma_f32_16x16x32_f16(pf, bv,
                                                                  oacc[dt], 0, 0, 0);
            }
        }
        // ---- store split fp16 ----
#pragma unroll
        for (int dt = 0; dt < 2; ++dt)
#pragma unroll
            for (int i = 0; i < 4; ++i) {
                const int srow = s0 + r0 + quad * 4 + i;
                if (srow < SS) {
                    size_t off = (size_t)(b * SS + srow) * DD + cb + ch * 32 +
                                 dt * 16 + l16;
                    unsigned short hh, ll;
                    split1h(oacc[dt][i], hh, ll);
                    Xh[off] = hh;
                    Xl[off] = ll;
                }
            }
    }
}

// ---------------------------------------------------------------------------
extern "C" void kernel_launch(void* const* d_in, const int* in_sizes, int n_in,
                              void* d_out, int out_size, void* d_ws,
                              size_t ws_size, hipStream_t stream)
{
    const float* hidden = (const float*)d_in[0];
    const int* tki = (const int*)d_in[1];
    const float* tkg = (const float*)d_in[2];
    const float* wq = (const float*)d_in[3];
    const float* Aq = (const float*)d_in[4];
    const float* Bq = (const float*)d_in[5];
    const float* bq = (const float*)d_in[6];
    const float* wk = (const float*)d_in[7];
    const float* Ak = (const float*)d_in[8];
    const float* Bk = (const float*)d_in[9];
    const float* bkb = (const float*)d_in[10];
    const float* wv = (const float*)d_in[11];
    const float* Av = (const float*)d_in[12];
    const float* Bv = (const float*)d_in[13];
    const float* bvb = (const float*)d_in[14];
    const float* wo = (const float*)d_in[15];
    const float* Ao = (const float*)d_in[16];
    const float* Bo = (const float*)d_in[17];
    const float* bob = (const float*)d_in[18];
    float* out = (float*)d_out;

    // ---- workspace carve-up ----
    char* ws = (char*)d_ws;
    const size_t MD_H = (size_t)MTOT * DD * 2;
    const size_t MPD_H = (size_t)MPAD * DD * 2;
    const size_t W_H = (size_t)DD * DD * 2;
    const size_t BC_H = (size_t)BB * DD * 32 * 2;
    const size_t XA_H = (size_t)MTOT * 32 * 2;

    unsigned short* qh = (unsigned short*)ws;  ws += MD_H;
    unsigned short* vh = (unsigned short*)ws;  ws += MD_H;
    unsigned short* Xh = (unsigned short*)ws;  ws += MPD_H;
    unsigned short* Xl = (unsigned short*)ws;  ws += MPD_H;
    unsigned short* Wh = (unsigned short*)ws;  ws += W_H;
    unsigned short* Bch = (unsigned short*)ws; ws += BC_H;
    unsigned short* xhq = (unsigned short*)ws; ws += XA_H;
    unsigned short* xhk = (unsigned short*)ws; ws += XA_H;
    unsigned short* xhv = (unsigned short*)ws; ws += XA_H;
    unsigned short* xho = (unsigned short*)ws; ws += XA_H;
    unsigned short* kh = (unsigned short*)d_out; // parked; dead before o-GEMM

    const long NX_V = (long)MTOT * DD, NX_T = (long)MPAD * DD;
    const long NW = (long)DD * DD;

    dim3 blk(256);
    dim3 gsX(NX_T / 1024);
    dim3 gsW(NW / 1024);
    dim3 gbc(128, BB);
    dim3 gxa3(5, BB * KEXP);
    dim3 gxa1(5, BB);
    dim3 ggemm(8, 65);
    dim3 gattn(HH, BB);

    split16_kernel<<<gsX, blk, 0, stream>>>(hidden, Xh, Xl, NX_V, NX_T);
    xa_qkv<<<gxa3, blk, 0, stream>>>(hidden, Aq, Ak, Av, tki, tkg, xhq, xhk,
                                     xhv);
    // Q
    split16_kernel<<<gsW, blk, 0, stream>>>(wq, Wh, nullptr, NW, NW);
    bcat_kernel<<<gbc, blk, 0, stream>>>(Bq, tki, Bch);
    gemm_mfma<<<ggemm, blk, 0, stream>>>(Xh, Xl, Wh, bq, xhq, Bch, nullptr,
                                         qh, 0.125f);
    // K
    split16_kernel<<<gsW, blk, 0, stream>>>(wk, Wh, nullptr, NW, NW);
    bcat_kernel<<<gbc, blk, 0, stream>>>(Bk, tki, Bch);
    gemm_mfma<<<ggemm, blk, 0, stream>>>(Xh, Xl, Wh, bkb, xhk, Bch, nullptr,
                                         kh, 1.0f);
    // V
    split16_kernel<<<gsW, blk, 0, stream>>>(wv, Wh, nullptr, NW, NW);
    bcat_kernel<<<gbc, blk, 0, stream>>>(Bv, tki, Bch);
    gemm_mfma<<<ggemm, blk, 0, stream>>>(Xh, Xl, Wh, bvb, xhv, Bch, nullptr,
                                         vh, 1.0f);

    // attention: overwrites Xh/Xl with fp16 split of attn output
    attn_v3<<<gattn, dim3(512), 0, stream>>>(qh, kh, vh, Xh, Xl);

    // O projection
    xa_o<<<gxa1, blk, 0, stream>>>(Xh, Xl, Ao, tki, tkg, xho);
    split16_kernel<<<gsW, blk, 0, stream>>>(wo, Wh, nullptr, NW, NW);
    bcat_kernel<<<gbc, blk, 0, stream>>>(Bo, tki, Bch);
    gemm_mfma<<<ggemm, blk, 0, stream>>>(Xh, Xl, Wh, bob, xho, Bch, out,
                                         nullptr, 1.0f);
}

// Round 6
// 404.570 us; speedup vs baseline: 6.6887x; 1.4474x over previous
//
#include <hip/hip_runtime.h>

// ViTMoEAttention: B=32,S=257,D=1024,H=16,HD=64,E=8,R=16,K=2
// Round 6:
//  - xa via MFMA: dense XA = X · A^T over ALL experts (N=384 qkv / 128 o);
//    per-sample expert gather moved into the GEMM LoRA tail; gates folded
//    into Bcat (exact).
//  - Pure fp16 GEMMs (dropped X lo term): W-hi rounding already contributes
//    the same ~1.8e-4 rms, so lo only bought sqrt(2). 1 MFMA product/chunk.
//  - q/k/v merged into ONE GEMM dispatch (Wcat [3072][1024], grid 24x65).
//  - attn unchanged except single-fp16 output written in-place over Xf.

#define BB 32
#define SS 257
#define DD 1024
#define HH 16
#define HDIM 64
#define EE 8
#define RR 16
#define KEXP 2
#define MTOT (BB * SS)   // 8224
#define MPAD 8320        // 65 * 128

typedef __attribute__((ext_vector_type(8))) _Float16 f16x8;
typedef __attribute__((ext_vector_type(4))) float f32x4;

static __device__ __forceinline__ float4 ld4(const float* p) {
    return *(const float4*)p;
}
static __device__ __forceinline__ unsigned short f16bits(_Float16 v) {
    union { _Float16 f; unsigned short u; } cv; cv.f = v; return cv.u;
}

static __device__ __forceinline__ void gl_lds16(const unsigned short* g,
                                                unsigned short* l) {
    __builtin_amdgcn_global_load_lds(
        (const __attribute__((address_space(1))) unsigned int*)g,
        (__attribute__((address_space(3))) unsigned int*)l, 16, 0, 0);
}

// ---------------------------------------------------------------------------
// cvt16_kernel: fp32 -> fp16 (RNE); pads [nvalid, ntotal) with 0.
// ---------------------------------------------------------------------------
__global__ __launch_bounds__(256) void cvt16_kernel(
    const float* __restrict__ src, unsigned short* __restrict__ h,
    long nvalid, long ntotal)
{
    long i = ((long)blockIdx.x * 256 + threadIdx.x) * 4;
    if (i >= ntotal) return;
    float4 v = (i < nvalid) ? ld4(&src[i]) : make_float4(0.f, 0.f, 0.f, 0.f);
    ushort4 hv;
    hv.x = f16bits((_Float16)v.x);
    hv.y = f16bits((_Float16)v.y);
    hv.z = f16bits((_Float16)v.z);
    hv.w = f16bits((_Float16)v.w);
    *(ushort4*)&h[i] = hv;
}

// ---------------------------------------------------------------------------
// bcat: out[b][pofs+n][kk] = gate[b][ke] * Ball[idx[b][ke]][n][r], kk=ke*16+r
// fp16, gate folded. grid (128, BB).
// ---------------------------------------------------------------------------
__global__ __launch_bounds__(256) void bcat_kernel(
    const float* __restrict__ Ball, const int* __restrict__ idx,
    const float* __restrict__ gates, unsigned short* __restrict__ h,
    int nstride, int pofs)
{
    int b = blockIdx.y;
    int i = blockIdx.x * 256 + threadIdx.x; // 0..32767
    int n = i >> 5, kk = i & 31;
    int ke = kk >> 4, r = kk & 15;
    int e = idx[b * KEXP + ke];
    float g = gates[b * KEXP + ke];
    float x = g * Ball[((size_t)e * DD + n) * RR + r];
    h[((size_t)b * nstride + pofs + n) * 32 + kk] = f16bits((_Float16)x);
}

// ---------------------------------------------------------------------------
// shared compute macro: one fp16 MFMA product per (i,j)
// ---------------------------------------------------------------------------
#define COMPUTE1()                                                             \
    do {                                                                       \
        f16x8 af[4], bf[4];                                                    \
        const int sb = (quad ^ ((l16 >> 1) & 3)) * 8;                          \
        _Pragma("unroll") for (int t = 0; t < 4; ++t) {                        \
            af[t] = *(const f16x8*)&Ah[(wm + t * 16 + l16) * 32 + sb];         \
            bf[t] = *(const f16x8*)&Bh[(wn + t * 16 + l16) * 32 + sb];         \
        }                                                                      \
        _Pragma("unroll") for (int i = 0; i < 4; ++i)                          \
        _Pragma("unroll") for (int j = 0; j < 4; ++j)                          \
            acc[i][j] = __builtin_amdgcn_mfma_f32_16x16x32_f16(                \
                af[i], bf[j], acc[i][j], 0, 0, 0);                             \
    } while (0)

// ---------------------------------------------------------------------------
// gemm_xa: XA[m][p*128+n] = sum_d Xf[m][d] * Ap[n][d]  (all experts, no gate)
// grid (npt, 65), npt in {3 (qkv), 1 (o)}. ncols = npt*128.
// ---------------------------------------------------------------------------
__global__ __launch_bounds__(256) void gemm_xa(
    const unsigned short* __restrict__ Xf, const unsigned short* __restrict__ A0,
    const unsigned short* __restrict__ A1, const unsigned short* __restrict__ A2,
    unsigned short* __restrict__ XA, int ncols)
{
    __shared__ unsigned short Ah[128 * 32];
    __shared__ unsigned short Bh[128 * 32];
    const int tid = threadIdx.x;
    const int m0 = blockIdx.y * 128;
    const int p = blockIdx.x;
    const unsigned short* Ap = (p == 0) ? A0 : (p == 1) ? A1 : A2;
    const int lane = tid & 63;
    const int w = tid >> 6;
    const int wm = (w >> 1) * 64;
    const int wn = (w & 1) * 64;
    const int l16 = lane & 15;
    const int quad = lane >> 4;

    f32x4 acc[4][4];
#pragma unroll
    for (int i = 0; i < 4; ++i)
#pragma unroll
        for (int j = 0; j < 4; ++j) acc[i][j] = (f32x4){0.f, 0.f, 0.f, 0.f};

    const int srow = tid >> 2;
    const int scol = (((tid & 3) ^ ((tid >> 3) & 3))) * 8;
    const int lbase = (tid & 192) * 8;
    const size_t xr0 = (size_t)(m0 + srow) * DD + scol;
    const size_t xr1 = (size_t)(m0 + srow + 64) * DD + scol;
    const size_t ar0 = (size_t)srow * DD + scol;
    const size_t ar1 = (size_t)(srow + 64) * DD + scol;

#pragma unroll 1
    for (int kt = 0; kt < 32; ++kt) {
        const int k0 = kt * 32;
        gl_lds16(Xf + xr0 + k0, &Ah[lbase]);
        gl_lds16(Xf + xr1 + k0, &Ah[2048 + lbase]);
        gl_lds16(Ap + ar0 + k0, &Bh[lbase]);
        gl_lds16(Ap + ar1 + k0, &Bh[2048 + lbase]);
        __syncthreads();
        COMPUTE1();
        __syncthreads();
    }

#pragma unroll
    for (int j = 0; j < 4; ++j) {
        const int col = p * 128 + wn + j * 16 + l16;
#pragma unroll
        for (int i = 0; i < 4; ++i) {
            const int mb = m0 + wm + i * 16 + quad * 4;
#pragma unroll
            for (int rg = 0; rg < 4; ++rg) {
                const int m = mb + rg;
                if (m < MTOT)
                    XA[(size_t)m * ncols + col] =
                        f16bits((_Float16)acc[i][j][rg]);
            }
        }
    }
}

// ---------------------------------------------------------------------------
// gemm_qkv: merged q/k/v projection. grid (24, 65); p = bx>>3 selects proj.
// C_p[m][nl] = alpha_p*(Xf W_p^T + XAd_gathered Bccat_p^T + bias_p), fp16 out.
// ---------------------------------------------------------------------------
__global__ __launch_bounds__(256) void gemm_qkv(
    const unsigned short* __restrict__ Xf, const unsigned short* __restrict__ Wcat,
    const float* __restrict__ bq, const float* __restrict__ bk,
    const float* __restrict__ bv, const unsigned short* __restrict__ XAd,
    const unsigned short* __restrict__ Bccat, const int* __restrict__ idx,
    unsigned short* __restrict__ qh, unsigned short* __restrict__ kh,
    unsigned short* __restrict__ vh)
{
    __shared__ unsigned short Ah[128 * 32];
    __shared__ unsigned short Bh[128 * 32];
    const int tid = threadIdx.x;
    const int m0 = blockIdx.y * 128;
    const int bx = blockIdx.x;
    const int p = bx >> 3;
    const int n0g = bx * 128;        // row in Wcat [0,3072)
    const int nl0 = (bx & 7) * 128;  // col within projection [0,1024)
    const int lane = tid & 63;
    const int w = tid >> 6;
    const int wm = (w >> 1) * 64;
    const int wn = (w & 1) * 64;
    const int l16 = lane & 15;
    const int quad = lane >> 4;

    f32x4 acc[4][4];
#pragma unroll
    for (int i = 0; i < 4; ++i)
#pragma unroll
        for (int j = 0; j < 4; ++j) acc[i][j] = (f32x4){0.f, 0.f, 0.f, 0.f};

    const int srow = tid >> 2;
    const int scol = (((tid & 3) ^ ((tid >> 3) & 3))) * 8;
    const int lbase = (tid & 192) * 8;
    const size_t xr0 = (size_t)(m0 + srow) * DD + scol;
    const size_t xr1 = (size_t)(m0 + srow + 64) * DD + scol;
    const size_t wr0 = (size_t)(n0g + srow) * DD + scol;
    const size_t wr1 = (size_t)(n0g + srow + 64) * DD + scol;

#pragma unroll 1
    for (int kt = 0; kt < 32; ++kt) {
        const int k0 = kt * 32;
        gl_lds16(Xf + xr0 + k0, &Ah[lbase]);
        gl_lds16(Xf + xr1 + k0, &Ah[2048 + lbase]);
        gl_lds16(Wcat + wr0 + k0, &Bh[lbase]);
        gl_lds16(Wcat + wr1 + k0, &Bh[2048 + lbase]);
        __syncthreads();
        COMPUTE1();
        __syncthreads();
    }

    // ---- LoRA tail: one masked K=32 chunk per batch in this m-tile ----
    {
        int m_hi = m0 + 127;
        if (m_hi >= MTOT) m_hi = MTOT - 1;
        const int b_first = m0 / SS;
        const int b_last = m_hi / SS;
        const int r = tid >> 1;
        const int key = (r >> 1) & 3;
        const int b0 = (tid & 1) * 2;
        const uint4 z = make_uint4(0, 0, 0, 0);
#pragma unroll 1
        for (int bp = b_first; bp <= b_last; ++bp) {
            const int gm = m0 + r;
            const bool va = (gm < MTOT) && (gm / SS == bp);
            const int g0 = b0 ^ key, g1 = (b0 + 1) ^ key;
            uint4 av0 = z, av1 = z;
            if (va) {
                const int e0 = idx[bp * 2 + (g0 >> 1)];
                const int e1 = idx[bp * 2 + (g1 >> 1)];
                av0 = *(const uint4*)&XAd[(size_t)gm * 384 + p * 128 +
                                          e0 * 16 + (g0 & 1) * 8];
                av1 = *(const uint4*)&XAd[(size_t)gm * 384 + p * 128 +
                                          e1 * 16 + (g1 & 1) * 8];
            }
            const size_t bo = ((size_t)bp * 3072 + p * 1024 + nl0 + r) * 32;
            uint4 bv0 = *(const uint4*)&Bccat[bo + g0 * 8];
            uint4 bv1 = *(const uint4*)&Bccat[bo + g1 * 8];
            __syncthreads();
            *(uint4*)&Ah[r * 32 + b0 * 8] = av0;
            *(uint4*)&Ah[r * 32 + (b0 + 1) * 8] = av1;
            *(uint4*)&Bh[r * 32 + b0 * 8] = bv0;
            *(uint4*)&Bh[r * 32 + (b0 + 1) * 8] = bv1;
            __syncthreads();
            COMPUTE1();
            __syncthreads();
        }
    }

    // ---- epilogue ----
    const float* bias = (p == 0) ? bq : (p == 1) ? bk : bv;
    unsigned short* C = (p == 0) ? qh : (p == 1) ? kh : vh;
    const float alpha = (p == 0) ? 0.125f : 1.0f;
#pragma unroll
    for (int j = 0; j < 4; ++j) {
        const int nl = nl0 + wn + j * 16 + l16;
        const float bvl = bias[nl];
#pragma unroll
        for (int i = 0; i < 4; ++i) {
            const int mb = m0 + wm + i * 16 + quad * 4;
#pragma unroll
            for (int rg = 0; rg < 4; ++rg) {
                const int m = mb + rg;
                if (m < MTOT)
                    C[(size_t)m * DD + nl] =
                        f16bits((_Float16)(alpha * (acc[i][j][rg] + bvl)));
            }
        }
    }
}

// ---------------------------------------------------------------------------
// gemm_o: o-projection, fp32 out. grid (8, 65).
// ---------------------------------------------------------------------------
__global__ __launch_bounds__(256) void gemm_o(
    const unsigned short* __restrict__ Xf, const unsigned short* __restrict__ Wh,
    const float* __restrict__ bias, const unsigned short* __restrict__ XAo,
    const unsigned short* __restrict__ Bco, const int* __restrict__ idx,
    float* __restrict__ Cf)
{
    __shared__ unsigned short Ah[128 * 32];
    __shared__ unsigned short Bh[128 * 32];
    const int tid = threadIdx.x;
    const int m0 = blockIdx.y * 128;
    const int n0 = blockIdx.x * 128;
    const int lane = tid & 63;
    const int w = tid >> 6;
    const int wm = (w >> 1) * 64;
    const int wn = (w & 1) * 64;
    const int l16 = lane & 15;
    const int quad = lane >> 4;

    f32x4 acc[4][4];
#pragma unroll
    for (int i = 0; i < 4; ++i)
#pragma unroll
        for (int j = 0; j < 4; ++j) acc[i][j] = (f32x4){0.f, 0.f, 0.f, 0.f};

    const int srow = tid >> 2;
    const int scol = (((tid & 3) ^ ((tid >> 3) & 3))) * 8;
    const int lbase = (tid & 192) * 8;
    const size_t xr0 = (size_t)(m0 + srow) * DD + scol;
    const size_t xr1 = (size_t)(m0 + srow + 64) * DD + scol;
    const size_t wr0 = (size_t)(n0 + srow) * DD + scol;
    const size_t wr1 = (size_t)(n0 + srow + 64) * DD + scol;

#pragma unroll 1
    for (int kt = 0; kt < 32; ++kt) {
        const int k0 = kt * 32;
        gl_lds16(Xf + xr0 + k0, &Ah[lbase]);
        gl_lds16(Xf + xr1 + k0, &Ah[2048 + lbase]);
        gl_lds16(Wh + wr0 + k0, &Bh[lbase]);
        gl_lds16(Wh + wr1 + k0, &Bh[2048 + lbase]);
        __syncthreads();
        COMPUTE1();
        __syncthreads();
    }

    {
        int m_hi = m0 + 127;
        if (m_hi >= MTOT) m_hi = MTOT - 1;
        const int b_first = m0 / SS;
        const int b_last = m_hi / SS;
        const int r = tid >> 1;
        const int key = (r >> 1) & 3;
        const int b0 = (tid & 1) * 2;
        const uint4 z = make_uint4(0, 0, 0, 0);
#pragma unroll 1
        for (int bp = b_first; bp <= b_last; ++bp) {
            const int gm = m0 + r;
            const bool va = (gm < MTOT) && (gm / SS == bp);
            const int g0 = b0 ^ key, g1 = (b0 + 1) ^ key;
            uint4 av0 = z, av1 = z;
            if (va) {
                const int e0 = idx[bp * 2 + (g0 >> 1)];
                const int e1 = idx[bp * 2 + (g1 >> 1)];
                av0 = *(const uint4*)&XAo[(size_t)gm * 128 + e0 * 16 +
                                          (g0 & 1) * 8];
                av1 = *(const uint4*)&XAo[(size_t)gm * 128 + e1 * 16 +
                                          (g1 & 1) * 8];
            }
            const size_t bo = ((size_t)bp * 1024 + n0 + r) * 32;
            uint4 bv0 = *(const uint4*)&Bco[bo + g0 * 8];
            uint4 bv1 = *(const uint4*)&Bco[bo + g1 * 8];
            __syncthreads();
            *(uint4*)&Ah[r * 32 + b0 * 8] = av0;
            *(uint4*)&Ah[r * 32 + (b0 + 1) * 8] = av1;
            *(uint4*)&Bh[r * 32 + b0 * 8] = bv0;
            *(uint4*)&Bh[r * 32 + (b0 + 1) * 8] = bv1;
            __syncthreads();
            COMPUTE1();
            __syncthreads();
        }
    }

#pragma unroll
    for (int j = 0; j < 4; ++j) {
        const int n = n0 + wn + j * 16 + l16;
        const float bvl = bias[n];
#pragma unroll
        for (int i = 0; i < 4; ++i) {
            const int mb = m0 + wm + i * 16 + quad * 4;
#pragma unroll
            for (int rg = 0; rg < 4; ++rg) {
                const int m = mb + rg;
                if (m < MTOT) Cf[(size_t)m * DD + n] = acc[i][j][rg] + bvl;
            }
        }
    }
}

// ---------------------------------------------------------------------------
// attn_v3: one block per (b,h). K + V^T resident in LDS; 5 q-tiles of 64;
// register softmax; fp16 MFMA. Writes single fp16 in-place over Xf.
// ---------------------------------------------------------------------------
__global__ __launch_bounds__(512, 1) void attn_v3(
    const unsigned short* __restrict__ qh, const unsigned short* __restrict__ kh,
    const unsigned short* __restrict__ vh, unsigned short* __restrict__ Xf)
{
    __shared__ unsigned short Ks[288 * 64];
    __shared__ unsigned short Vt[64 * 312];
    __shared__ unsigned short Qs[64 * 64];
    __shared__ unsigned short Ps[64 * 312];
    __shared__ float sredm[2][64];
    __shared__ float sreds[2][64];

    const int tid = threadIdx.x;
    const int h = blockIdx.x, b = blockIdx.y;
    const int cb = h * HDIM;
    const int lane = tid & 63;
    const int w = tid >> 6;
    const int r0 = (w & 3) * 16;
    const int ch = w >> 2;
    const int l16 = lane & 15;
    const int quad = lane >> 4;

    const size_t kbase = (size_t)(b * SS) * DD + cb;
    {
        const int rr = w * 8 + (lane >> 3);
        const int cg = ((lane & 7) ^ (rr & 7)) * 8;
#pragma unroll
        for (int c = 0; c < 4; ++c)
            gl_lds16(kh + kbase + (size_t)(c * 64 + rr) * DD + cg,
                     &Ks[(c * 64 + w * 8) * 64]);
    }
    if (tid < 256) {
        uint4 z = make_uint4(0, 0, 0, 0);
        if (tid < 8) z = *(const uint4*)&kh[kbase + (size_t)256 * DD + tid * 8];
        *(uint4*)&Ks[256 * 64 + tid * 8] = z;
    }
    {
        uint4 z = make_uint4(0, 0, 0, 0);
        for (int i = tid; i < 2496; i += 512) *(uint4*)&Vt[i * 8] = z;
    }
    __syncthreads();
    if (tid < SS) {
        const size_t vbase = (size_t)(b * SS + tid) * DD + cb;
#pragma unroll
        for (int dc = 0; dc < 8; ++dc) {
            uint4 vv = *(const uint4*)&vh[vbase + dc * 8];
            unsigned short vs[8];
            *(uint4*)vs = vv;
#pragma unroll
            for (int u = 0; u < 8; ++u) Vt[(dc * 8 + u) * 312 + tid] = vs[u];
        }
    }

#pragma unroll 1
    for (int qt = 0; qt < 5; ++qt) {
        const int s0 = qt * 64;
        __syncthreads();
        {
            int sg = s0 + (tid >> 3);
            if (sg > SS - 1) sg = SS - 1;
            const int cg = ((tid & 7) ^ ((tid >> 3) & 7)) * 8;
            gl_lds16(qh + (size_t)(b * SS + sg) * DD + cb + cg,
                     &Qs[(w * 8) * 64]);
        }
        __syncthreads();

        f32x4 lac[9];
#pragma unroll
        for (int ct = 0; ct < 9; ++ct) lac[ct] = (f32x4){0.f, 0.f, 0.f, 0.f};
#pragma unroll
        for (int kc = 0; kc < 2; ++kc) {
            const int sb = ((kc * 4 + quad) ^ (l16 & 7)) * 8;
            f16x8 af = *(const f16x8*)&Qs[(r0 + l16) * 64 + sb];
#pragma unroll
            for (int ct = 0; ct < 9; ++ct) {
                const int c0 = ch * 144 + ct * 16;
                f16x8 bf = *(const f16x8*)&Ks[(c0 + l16) * 64 + sb];
                lac[ct] = __builtin_amdgcn_mfma_f32_16x16x32_f16(af, bf,
                                                                 lac[ct], 0, 0, 0);
            }
        }
#pragma unroll
        for (int ct = 0; ct < 9; ++ct) {
            const int t = ch * 144 + ct * 16 + l16;
            if (t > SS - 1) {
                lac[ct][0] = -1e30f; lac[ct][1] = -1e30f;
                lac[ct][2] = -1e30f; lac[ct][3] = -1e30f;
            }
        }
        float mx[4] = {-1e30f, -1e30f, -1e30f, -1e30f};
#pragma unroll
        for (int ct = 0; ct < 9; ++ct)
#pragma unroll
            for (int i = 0; i < 4; ++i) mx[i] = fmaxf(mx[i], lac[ct][i]);
#pragma unroll
        for (int o = 1; o < 16; o <<= 1)
#pragma unroll
            for (int i = 0; i < 4; ++i)
                mx[i] = fmaxf(mx[i], __shfl_xor(mx[i], o, 16));
        if (l16 == 0)
#pragma unroll
            for (int i = 0; i < 4; ++i) sredm[ch][r0 + quad * 4 + i] = mx[i];
        __syncthreads();
#pragma unroll
        for (int i = 0; i < 4; ++i)
            mx[i] = fmaxf(mx[i], sredm[1 - ch][r0 + quad * 4 + i]);
        float sm[4] = {0.f, 0.f, 0.f, 0.f};
#pragma unroll
        for (int ct = 0; ct < 9; ++ct)
#pragma unroll
            for (int i = 0; i < 4; ++i) {
                float p = __expf(lac[ct][i] - mx[i]);
                lac[ct][i] = p;
                sm[i] += p;
            }
#pragma unroll
        for (int o = 1; o < 16; o <<= 1)
#pragma unroll
            for (int i = 0; i < 4; ++i) sm[i] += __shfl_xor(sm[i], o, 16);
        if (l16 == 0)
#pragma unroll
            for (int i = 0; i < 4; ++i) sreds[ch][r0 + quad * 4 + i] = sm[i];
        __syncthreads();
        float inv[4];
#pragma unroll
        for (int i = 0; i < 4; ++i)
            inv[i] = 1.f / (sm[i] + sreds[1 - ch][r0 + quad * 4 + i]);
#pragma unroll
        for (int ct = 0; ct < 9; ++ct) {
            const int col = ch * 144 + ct * 16 + l16;
#pragma unroll
            for (int i = 0; i < 4; ++i)
                Ps[(r0 + quad * 4 + i) * 312 + col] =
                    f16bits((_Float16)(lac[ct][i] * inv[i]));
        }
        __syncthreads();

        f32x4 oacc[2];
        oacc[0] = (f32x4){0.f, 0.f, 0.f, 0.f};
        oacc[1] = (f32x4){0.f, 0.f, 0.f, 0.f};
#pragma unroll
        for (int tt = 0; tt < 9; ++tt) {
            const int t0 = tt * 32;
            f16x8 pf = *(const f16x8*)&Ps[(r0 + l16) * 312 + t0 + quad * 8];
#pragma unroll
            for (int dt = 0; dt < 2; ++dt) {
                f16x8 bv = *(const f16x8*)&Vt[(ch * 32 + dt * 16 + l16) * 312 +
                                              t0 + quad * 8];
                oacc[dt] = __builtin_amdgcn_mfma_f32_16x16x32_f16(pf, bv,
                                                                  oacc[dt], 0, 0, 0);
            }
        }
#pragma unroll
        for (int dt = 0; dt < 2; ++dt)
#pragma unroll
            for (int i = 0; i < 4; ++i) {
                const int srow = s0 + r0 + quad * 4 + i;
                if (srow < SS) {
                    size_t off = (size_t)(b * SS + srow) * DD + cb + ch * 32 +
                                 dt * 16 + l16;
                    Xf[off] = f16bits((_Float16)oacc[dt][i]);
                }
            }
    }
}

// ---------------------------------------------------------------------------
extern "C" void kernel_launch(void* const* d_in, const int* in_sizes, int n_in,
                              void* d_out, int out_size, void* d_ws,
                              size_t ws_size, hipStream_t stream)
{
    const float* hidden = (const float*)d_in[0];
    const int* tki = (const int*)d_in[1];
    const float* tkg = (const float*)d_in[2];
    const float* wq = (const float*)d_in[3];
    const float* Aq = (const float*)d_in[4];
    const float* Bq = (const float*)d_in[5];
    const float* bq = (const float*)d_in[6];
    const float* wk = (const float*)d_in[7];
    const float* Ak = (const float*)d_in[8];
    const float* Bk = (const float*)d_in[9];
    const float* bkb = (const float*)d_in[10];
    const float* wv = (const float*)d_in[11];
    const float* Av = (const float*)d_in[12];
    const float* Bv = (const float*)d_in[13];
    const float* bvb = (const float*)d_in[14];
    const float* wo = (const float*)d_in[15];
    const float* Ao = (const float*)d_in[16];
    const float* Bo = (const float*)d_in[17];
    const float* bob = (const float*)d_in[18];
    float* out = (float*)d_out;

    // ---- workspace (~66 MB) ----
    char* ws = (char*)d_ws;
    const size_t MD_H = (size_t)MTOT * DD * 2;   // 16.84 MB
    const size_t MPD_H = (size_t)MPAD * DD * 2;  // 17.04 MB
    const size_t W_H = (size_t)DD * DD * 2;      // 2.10 MB
    const size_t A_H = (size_t)EE * RR * DD * 2; // 0.26 MB

    unsigned short* Xf = (unsigned short*)ws;    ws += MPD_H;
    unsigned short* qh = (unsigned short*)ws;    ws += MD_H;
    unsigned short* vh = (unsigned short*)ws;    ws += MD_H;
    unsigned short* Wcat = (unsigned short*)ws;  ws += 3 * W_H;
    unsigned short* Bccat = (unsigned short*)ws; ws += (size_t)BB * 3072 * 32 * 2;
    unsigned short* XAo = (unsigned short*)ws;   ws += (size_t)MTOT * 128 * 2;
    unsigned short* Aq16 = (unsigned short*)ws;  ws += A_H;
    unsigned short* Ak16 = (unsigned short*)ws;  ws += A_H;
    unsigned short* Av16 = (unsigned short*)ws;  ws += A_H;
    // parked in d_out (dead before gemm_o writes out):
    unsigned short* kh = (unsigned short*)d_out;
    unsigned short* XAd = (unsigned short*)((char*)d_out + MD_H);
    // aliases (stream-ordered after their previous readers are done):
    unsigned short* Who = Wcat;
    unsigned short* Bco = Bccat;
    unsigned short* Ao16 = Aq16;

    const long NX_V = (long)MTOT * DD, NX_T = (long)MPAD * DD;
    const long NW = (long)DD * DD;
    const long NA = (long)EE * RR * DD; // 131072

    dim3 blk(256);
    dim3 gsX(NX_T / 1024);
    dim3 gsW(NW / 1024);
    dim3 gsA(NA / 1024);
    dim3 gbc(128, BB);
    dim3 gxad(3, 65);
    dim3 gxao(1, 65);
    dim3 gqkv(24, 65);
    dim3 go(8, 65);
    dim3 gattn(HH, BB);

    cvt16_kernel<<<gsX, blk, 0, stream>>>(hidden, Xf, NX_V, NX_T);
    cvt16_kernel<<<gsW, blk, 0, stream>>>(wq, Wcat, NW, NW);
    cvt16_kernel<<<gsW, blk, 0, stream>>>(wk, Wcat + NW, NW, NW);
    cvt16_kernel<<<gsW, blk, 0, stream>>>(wv, Wcat + 2 * NW, NW, NW);
    cvt16_kernel<<<gsA, blk, 0, stream>>>(Aq, Aq16, NA, NA);
    cvt16_kernel<<<gsA, blk, 0, stream>>>(Ak, Ak16, NA, NA);
    cvt16_kernel<<<gsA, blk, 0, stream>>>(Av, Av16, NA, NA);
    bcat_kernel<<<gbc, blk, 0, stream>>>(Bq, tki, tkg, Bccat, 3072, 0);
    bcat_kernel<<<gbc, blk, 0, stream>>>(Bk, tki, tkg, Bccat, 3072, 1024);
    bcat_kernel<<<gbc, blk, 0, stream>>>(Bv, tki, tkg, Bccat, 3072, 2048);

    gemm_xa<<<gxad, blk, 0, stream>>>(Xf, Aq16, Ak16, Av16, XAd, 384);
    gemm_qkv<<<gqkv, blk, 0, stream>>>(Xf, Wcat, bq, bkb, bvb, XAd, Bccat,
                                       tki, qh, kh, vh);

    attn_v3<<<gattn, dim3(512), 0, stream>>>(qh, kh, vh, Xf);

    // o projection (aliased buffers: Wcat/Bccat/Aq16 are dead now)
    cvt16_kernel<<<gsA, blk, 0, stream>>>(Ao, Ao16, NA, NA);
    bcat_kernel<<<gbc, blk, 0, stream>>>(Bo, tki, tkg, Bco, 1024, 0);
    cvt16_kernel<<<gsW, blk, 0, stream>>>(wo, Who, NW, NW);
    gemm_xa<<<gxao, blk, 0, stream>>>(Xf, Ao16, Ao16, Ao16, XAo, 128);
    gemm_o<<<go, blk, 0, stream>>>(Xf, Who, bob, XAo, Bco, tki, out);
}

// Round 7
// 380.934 us; speedup vs baseline: 7.1037x; 1.0620x over previous
//
#include <hip/hip_runtime.h>

// ViTMoEAttention: B=32,S=257,D=1024,H=16,HD=64,E=8,R=16,K=2
// Round 7:
//  - gemm_qkv v-blocks emit V^T directly (LDS-transposed epilogue) into
//    vT[(b*16+h)*64+d][t] (t-stride 264). attn_v4 stages it with uint4
//    copies — the 16K-scalar-ds_write transpose is gone from attention.
//  - q/k epilogues route through LDS -> uint4 coalesced global stores
//    (WRITE_SIZE was 2.3x ideal from 32B fragment scatter).
//  - Single fused `prep` kernel (blockIdx-routed) replaces 12 cvt/bcat
//    dispatches; bcat vectorized (16 contiguous floats/thread).
// GEMM core (128x128, BK=32, fp16 MFMA, XOR-swizzled LDS) unchanged.

#define BB 32
#define SS 257
#define DD 1024
#define HH 16
#define HDIM 64
#define EE 8
#define RR 16
#define MTOT (BB * SS)   // 8224
#define MPAD 8320        // 65 * 128
#define VTS 264          // vT t-stride (257 pad to 264)

typedef __attribute__((ext_vector_type(8))) _Float16 f16x8;
typedef __attribute__((ext_vector_type(4))) float f32x4;

static __device__ __forceinline__ float4 ld4(const float* p) {
    return *(const float4*)p;
}
static __device__ __forceinline__ unsigned short f16b(float x) {
    union { _Float16 f; unsigned short u; } cv;
    cv.f = (_Float16)x;
    return cv.u;
}

static __device__ __forceinline__ void gl_lds16(const unsigned short* g,
                                                unsigned short* l) {
    __builtin_amdgcn_global_load_lds(
        (const __attribute__((address_space(1))) unsigned int*)g,
        (__attribute__((address_space(3))) unsigned int*)l, 16, 0, 0);
}

// ---------------------------------------------------------------------------
// prep: ALL preprocessing in one dispatch, routed by blockIdx.x:
//   [0,8320)        X cvt fp32->fp16 (padded to MPAD rows)
//   [8320,12416)    W cvt x4 -> Wcat(q,k,v) / Who
//   [12416,12928)   A cvt x4 -> A3(q,k,v) / Ao16
//   [12928,13952)   bcat x4 (gates folded) -> Bccat(q,k,v) / Bco
// ---------------------------------------------------------------------------
__global__ __launch_bounds__(256) void prep(
    const float* __restrict__ hidden, const float* __restrict__ wq,
    const float* __restrict__ wk, const float* __restrict__ wv,
    const float* __restrict__ wo, const float* __restrict__ Aq,
    const float* __restrict__ Ak, const float* __restrict__ Av,
    const float* __restrict__ Ao, const float* __restrict__ Bq,
    const float* __restrict__ Bk, const float* __restrict__ Bv,
    const float* __restrict__ Bo, const int* __restrict__ tki,
    const float* __restrict__ tkg, unsigned short* __restrict__ Xf,
    unsigned short* __restrict__ Wcat, unsigned short* __restrict__ Who,
    unsigned short* __restrict__ A3, unsigned short* __restrict__ Ao16,
    unsigned short* __restrict__ Bccat, unsigned short* __restrict__ Bco)
{
    const int tid = threadIdx.x;
    int bx = blockIdx.x;
    if (bx < 8320) { // X
        long i = ((long)bx * 256 + tid) * 4;
        float4 v = (i < (long)MTOT * DD) ? ld4(&hidden[i])
                                         : make_float4(0.f, 0.f, 0.f, 0.f);
        ushort4 hv;
        hv.x = f16b(v.x); hv.y = f16b(v.y); hv.z = f16b(v.z); hv.w = f16b(v.w);
        *(ushort4*)&Xf[i] = hv;
        return;
    }
    bx -= 8320;
    if (bx < 4096) { // W x4
        const int sel = bx >> 10;
        long i = ((long)(bx & 1023) * 256 + tid) * 4;
        const float* src = (sel == 0) ? wq : (sel == 1) ? wk
                                          : (sel == 2) ? wv : wo;
        unsigned short* dst =
            (sel < 3) ? Wcat + (size_t)sel * DD * DD : Who;
        float4 v = ld4(&src[i]);
        ushort4 hv;
        hv.x = f16b(v.x); hv.y = f16b(v.y); hv.z = f16b(v.z); hv.w = f16b(v.w);
        *(ushort4*)&dst[i] = hv;
        return;
    }
    bx -= 4096;
    if (bx < 512) { // A x4
        const int sel = bx >> 7;
        long i = ((long)(bx & 127) * 256 + tid) * 4;
        const float* src = (sel == 0) ? Aq : (sel == 1) ? Ak
                                          : (sel == 2) ? Av : Ao;
        unsigned short* dst =
            (sel < 3) ? A3 + (size_t)sel * EE * RR * DD : Ao16;
        float4 v = ld4(&src[i]);
        ushort4 hv;
        hv.x = f16b(v.x); hv.y = f16b(v.y); hv.z = f16b(v.z); hv.w = f16b(v.w);
        *(ushort4*)&dst[i] = hv;
        return;
    }
    bx -= 512;
    { // bcat x4: thread handles one (b, n, ke) -> 16 contiguous r values
        const int set = bx >> 8;
        const int i = (bx & 255) * 256 + tid; // 0..65535
        const int b = i >> 11;
        const int rem = i & 2047;
        const int n = rem >> 1;
        const int ke = rem & 1;
        const float* Ball = (set == 0) ? Bq : (set == 1) ? Bk
                                           : (set == 2) ? Bv : Bo;
        const int e = tki[b * 2 + ke];
        const float g = tkg[b * 2 + ke];
        const float* sp = &Ball[((size_t)e * DD + n) * RR];
        unsigned short o16[16];
#pragma unroll
        for (int r4 = 0; r4 < 4; ++r4) {
            float4 v = ld4(sp + r4 * 4);
            o16[r4 * 4 + 0] = f16b(g * v.x);
            o16[r4 * 4 + 1] = f16b(g * v.y);
            o16[r4 * 4 + 2] = f16b(g * v.z);
            o16[r4 * 4 + 3] = f16b(g * v.w);
        }
        unsigned short* dst =
            (set < 3) ? &Bccat[((size_t)b * 3072 + set * 1024 + n) * 32 + ke * 16]
                      : &Bco[((size_t)b * 1024 + n) * 32 + ke * 16];
        *(uint4*)&dst[0] = *(uint4*)&o16[0];
        *(uint4*)&dst[8] = *(uint4*)&o16[8];
    }
}

// ---------------------------------------------------------------------------
#define COMPUTE1()                                                             \
    do {                                                                       \
        f16x8 af[4], bf[4];                                                    \
        const int sb = (quad ^ ((l16 >> 1) & 3)) * 8;                          \
        _Pragma("unroll") for (int t = 0; t < 4; ++t) {                        \
            af[t] = *(const f16x8*)&Ah[(wm + t * 16 + l16) * 32 + sb];         \
            bf[t] = *(const f16x8*)&Bh[(wn + t * 16 + l16) * 32 + sb];         \
        }                                                                      \
        _Pragma("unroll") for (int i = 0; i < 4; ++i)                          \
        _Pragma("unroll") for (int j = 0; j < 4; ++j)                          \
            acc[i][j] = __builtin_amdgcn_mfma_f32_16x16x32_f16(                \
                af[i], bf[j], acc[i][j], 0, 0, 0);                             \
    } while (0)

// ---------------------------------------------------------------------------
// gemm_xa: XA[m][p*128+n] = Xf · Ap^T (all experts). grid (npt, 65).
// ---------------------------------------------------------------------------
__global__ __launch_bounds__(256) void gemm_xa(
    const unsigned short* __restrict__ Xf, const unsigned short* __restrict__ A0,
    const unsigned short* __restrict__ A1, const unsigned short* __restrict__ A2,
    unsigned short* __restrict__ XA, int ncols)
{
    __shared__ unsigned short Ah[128 * 32];
    __shared__ unsigned short Bh[128 * 32];
    const int tid = threadIdx.x;
    const int m0 = blockIdx.y * 128;
    const int p = blockIdx.x;
    const unsigned short* Ap = (p == 0) ? A0 : (p == 1) ? A1 : A2;
    const int lane = tid & 63;
    const int w = tid >> 6;
    const int wm = (w >> 1) * 64;
    const int wn = (w & 1) * 64;
    const int l16 = lane & 15;
    const int quad = lane >> 4;

    f32x4 acc[4][4];
#pragma unroll
    for (int i = 0; i < 4; ++i)
#pragma unroll
        for (int j = 0; j < 4; ++j) acc[i][j] = (f32x4){0.f, 0.f, 0.f, 0.f};

    const int srow = tid >> 2;
    const int scol = (((tid & 3) ^ ((tid >> 3) & 3))) * 8;
    const int lbase = (tid & 192) * 8;
    const size_t xr0 = (size_t)(m0 + srow) * DD + scol;
    const size_t xr1 = (size_t)(m0 + srow + 64) * DD + scol;
    const size_t ar0 = (size_t)srow * DD + scol;
    const size_t ar1 = (size_t)(srow + 64) * DD + scol;

#pragma unroll 1
    for (int kt = 0; kt < 32; ++kt) {
        const int k0 = kt * 32;
        gl_lds16(Xf + xr0 + k0, &Ah[lbase]);
        gl_lds16(Xf + xr1 + k0, &Ah[2048 + lbase]);
        gl_lds16(Ap + ar0 + k0, &Bh[lbase]);
        gl_lds16(Ap + ar1 + k0, &Bh[2048 + lbase]);
        __syncthreads();
        COMPUTE1();
        __syncthreads();
    }

#pragma unroll
    for (int j = 0; j < 4; ++j) {
        const int col = p * 128 + wn + j * 16 + l16;
#pragma unroll
        for (int i = 0; i < 4; ++i) {
            const int mb = m0 + wm + i * 16 + quad * 4;
#pragma unroll
            for (int rg = 0; rg < 4; ++rg) {
                const int m = mb + rg;
                if (m < MTOT)
                    XA[(size_t)m * ncols + col] = f16b(acc[i][j][rg]);
            }
        }
    }
}

// ---------------------------------------------------------------------------
// gemm_qkv: merged q/k/v. grid (24, 65); p = bx>>3. Epilogues via LDS:
// q/k row-major coalesced uint4; v transposed -> vT[(b*16+h)*64+d][t].
// ---------------------------------------------------------------------------
__global__ __launch_bounds__(256) void gemm_qkv(
    const unsigned short* __restrict__ Xf, const unsigned short* __restrict__ Wcat,
    const float* __restrict__ bq, const float* __restrict__ bk,
    const float* __restrict__ bv, const unsigned short* __restrict__ XAd,
    const unsigned short* __restrict__ Bccat, const int* __restrict__ idx,
    unsigned short* __restrict__ qh, unsigned short* __restrict__ kh,
    unsigned short* __restrict__ vTg)
{
    __shared__ unsigned short Ah[128 * 32];
    __shared__ unsigned short Bh[128 * 32];
    __shared__ unsigned short Epi[8704]; // 64x136 (row-major) or 128x68 (vT)
    const int tid = threadIdx.x;
    const int m0 = blockIdx.y * 128;
    const int bx = blockIdx.x;
    const int p = bx >> 3;
    const int n0g = bx * 128;
    const int nl0 = (bx & 7) * 128;
    const int lane = tid & 63;
    const int w = tid >> 6;
    const int wm = (w >> 1) * 64;
    const int wn = (w & 1) * 64;
    const int l16 = lane & 15;
    const int quad = lane >> 4;

    f32x4 acc[4][4];
#pragma unroll
    for (int i = 0; i < 4; ++i)
#pragma unroll
        for (int j = 0; j < 4; ++j) acc[i][j] = (f32x4){0.f, 0.f, 0.f, 0.f};

    const int srow = tid >> 2;
    const int scol = (((tid & 3) ^ ((tid >> 3) & 3))) * 8;
    const int lbase = (tid & 192) * 8;
    const size_t xr0 = (size_t)(m0 + srow) * DD + scol;
    const size_t xr1 = (size_t)(m0 + srow + 64) * DD + scol;
    const size_t wr0 = (size_t)(n0g + srow) * DD + scol;
    const size_t wr1 = (size_t)(n0g + srow + 64) * DD + scol;

#pragma unroll 1
    for (int kt = 0; kt < 32; ++kt) {
        const int k0 = kt * 32;
        gl_lds16(Xf + xr0 + k0, &Ah[lbase]);
        gl_lds16(Xf + xr1 + k0, &Ah[2048 + lbase]);
        gl_lds16(Wcat + wr0 + k0, &Bh[lbase]);
        gl_lds16(Wcat + wr1 + k0, &Bh[2048 + lbase]);
        __syncthreads();
        COMPUTE1();
        __syncthreads();
    }

    // ---- LoRA tail ----
    {
        int m_hi = m0 + 127;
        if (m_hi >= MTOT) m_hi = MTOT - 1;
        const int b_first = m0 / SS;
        const int b_last = m_hi / SS;
        const int r = tid >> 1;
        const int key = (r >> 1) & 3;
        const int b0 = (tid & 1) * 2;
        const uint4 z = make_uint4(0, 0, 0, 0);
#pragma unroll 1
        for (int bp = b_first; bp <= b_last; ++bp) {
            const int gm = m0 + r;
            const bool va = (gm < MTOT) && (gm / SS == bp);
            const int g0 = b0 ^ key, g1 = (b0 + 1) ^ key;
            uint4 av0 = z, av1 = z;
            if (va) {
                const int e0 = idx[bp * 2 + (g0 >> 1)];
                const int e1 = idx[bp * 2 + (g1 >> 1)];
                av0 = *(const uint4*)&XAd[(size_t)gm * 384 + p * 128 +
                                          e0 * 16 + (g0 & 1) * 8];
                av1 = *(const uint4*)&XAd[(size_t)gm * 384 + p * 128 +
                                          e1 * 16 + (g1 & 1) * 8];
            }
            const size_t bo = ((size_t)bp * 3072 + p * 1024 + nl0 + r) * 32;
            uint4 bv0 = *(const uint4*)&Bccat[bo + g0 * 8];
            uint4 bv1 = *(const uint4*)&Bccat[bo + g1 * 8];
            __syncthreads();
            *(uint4*)&Ah[r * 32 + b0 * 8] = av0;
            *(uint4*)&Ah[r * 32 + (b0 + 1) * 8] = av1;
            *(uint4*)&Bh[r * 32 + b0 * 8] = bv0;
            *(uint4*)&Bh[r * 32 + (b0 + 1) * 8] = bv1;
            __syncthreads();
            COMPUTE1();
            __syncthreads();
        }
    }

    // ---- epilogue via Epi LDS ----
    const float* bias = (p == 0) ? bq : (p == 1) ? bk : bv;
    if (p < 2) {
        const float alpha = (p == 0) ? 0.125f : 1.0f;
        unsigned short* C = (p == 0) ? qh : kh;
#pragma unroll 1
        for (int half = 0; half < 2; ++half) {
            if ((w >> 1) == half) {
#pragma unroll
                for (int j = 0; j < 4; ++j) {
                    const int nl = wn + j * 16 + l16;
                    const float bvl = bias[nl0 + nl];
#pragma unroll
                    for (int i = 0; i < 4; ++i) {
                        const int ml = i * 16 + quad * 4;
#pragma unroll
                        for (int rg = 0; rg < 4; ++rg)
                            Epi[(ml + rg) * 136 + nl] =
                                f16b(alpha * (acc[i][j][rg] + bvl));
                    }
                }
            }
            __syncthreads();
            {
                const int r = tid >> 2;
                const int c = (tid & 3) * 32;
                const int m = m0 + half * 64 + r;
                if (m < MTOT) {
#pragma unroll
                    for (int k = 0; k < 4; ++k)
                        *(uint4*)&C[(size_t)m * DD + nl0 + c + k * 8] =
                            *(const uint4*)&Epi[r * 136 + c + k * 8];
                }
            }
            __syncthreads();
        }
    } else {
        // v: transposed epilogue -> vT[(b*16+h)*64+d][t], t-stride VTS
#pragma unroll 1
        for (int half = 0; half < 2; ++half) {
            if ((w >> 1) == half) {
#pragma unroll
                for (int j = 0; j < 4; ++j) {
                    const int nl = wn + j * 16 + l16;
                    const float bvl = bias[nl0 + nl];
#pragma unroll
                    for (int i = 0; i < 4; ++i) {
                        const int ml = i * 16 + quad * 4;
                        ushort4 pk;
                        pk.x = f16b(acc[i][j][0] + bvl);
                        pk.y = f16b(acc[i][j][1] + bvl);
                        pk.z = f16b(acc[i][j][2] + bvl);
                        pk.w = f16b(acc[i][j][3] + bvl);
                        *(ushort4*)&Epi[nl * 68 + ml] = pk;
                    }
                }
            }
            __syncthreads();
            {
                const int tl = tid & 63;
                const int mg = m0 + half * 64 + tl;
                if (mg < MTOT) {
                    const int bq2 = mg / SS;
                    const int t = mg - bq2 * SS;
#pragma unroll 4
                    for (int k = 0; k < 32; ++k) {
                        const int nll = (tid >> 6) + k * 4;
                        const int d = nl0 + nll;
                        vTg[((size_t)(bq2 * HH + (d >> 6)) * HDIM + (d & 63)) *
                                VTS + t] = Epi[nll * 68 + tl];
                    }
                }
            }
            __syncthreads();
        }
    }
}

// ---------------------------------------------------------------------------
// gemm_o: o-projection, fp32 out (coalesced 64B/16-lane stores). grid (8,65).
// ---------------------------------------------------------------------------
__global__ __launch_bounds__(256) void gemm_o(
    const unsigned short* __restrict__ Xf, const unsigned short* __restrict__ Wh2,
    const float* __restrict__ bias, const unsigned short* __restrict__ XAo,
    const unsigned short* __restrict__ Bco, const int* __restrict__ idx,
    float* __restrict__ Cf)
{
    __shared__ unsigned short Ah[128 * 32];
    __shared__ unsigned short Bh[128 * 32];
    const int tid = threadIdx.x;
    const int m0 = blockIdx.y * 128;
    const int n0 = blockIdx.x * 128;
    const int lane = tid & 63;
    const int w = tid >> 6;
    const int wm = (w >> 1) * 64;
    const int wn = (w & 1) * 64;
    const int l16 = lane & 15;
    const int quad = lane >> 4;

    f32x4 acc[4][4];
#pragma unroll
    for (int i = 0; i < 4; ++i)
#pragma unroll
        for (int j = 0; j < 4; ++j) acc[i][j] = (f32x4){0.f, 0.f, 0.f, 0.f};

    const int srow = tid >> 2;
    const int scol = (((tid & 3) ^ ((tid >> 3) & 3))) * 8;
    const int lbase = (tid & 192) * 8;
    const size_t xr0 = (size_t)(m0 + srow) * DD + scol;
    const size_t xr1 = (size_t)(m0 + srow + 64) * DD + scol;
    const size_t wr0 = (size_t)(n0 + srow) * DD + scol;
    const size_t wr1 = (size_t)(n0 + srow + 64) * DD + scol;

#pragma unroll 1
    for (int kt = 0; kt < 32; ++kt) {
        const int k0 = kt * 32;
        gl_lds16(Xf + xr0 + k0, &Ah[lbase]);
        gl_lds16(Xf + xr1 + k0, &Ah[2048 + lbase]);
        gl_lds16(Wh2 + wr0 + k0, &Bh[lbase]);
        gl_lds16(Wh2 + wr1 + k0, &Bh[2048 + lbase]);
        __syncthreads();
        COMPUTE1();
        __syncthreads();
    }

    {
        int m_hi = m0 + 127;
        if (m_hi >= MTOT) m_hi = MTOT - 1;
        const int b_first = m0 / SS;
        const int b_last = m_hi / SS;
        const int r = tid >> 1;
        const int key = (r >> 1) & 3;
        const int b0 = (tid & 1) * 2;
        const uint4 z = make_uint4(0, 0, 0, 0);
#pragma unroll 1
        for (int bp = b_first; bp <= b_last; ++bp) {
            const int gm = m0 + r;
            const bool va = (gm < MTOT) && (gm / SS == bp);
            const int g0 = b0 ^ key, g1 = (b0 + 1) ^ key;
            uint4 av0 = z, av1 = z;
            if (va) {
                const int e0 = idx[bp * 2 + (g0 >> 1)];
                const int e1 = idx[bp * 2 + (g1 >> 1)];
                av0 = *(const uint4*)&XAo[(size_t)gm * 128 + e0 * 16 +
                                          (g0 & 1) * 8];
                av1 = *(const uint4*)&XAo[(size_t)gm * 128 + e1 * 16 +
                                          (g1 & 1) * 8];
            }
            const size_t bo = ((size_t)bp * 1024 + n0 + r) * 32;
            uint4 bv0 = *(const uint4*)&Bco[bo + g0 * 8];
            uint4 bv1 = *(const uint4*)&Bco[bo + g1 * 8];
            __syncthreads();
            *(uint4*)&Ah[r * 32 + b0 * 8] = av0;
            *(uint4*)&Ah[r * 32 + (b0 + 1) * 8] = av1;
            *(uint4*)&Bh[r * 32 + b0 * 8] = bv0;
            *(uint4*)&Bh[r * 32 + (b0 + 1) * 8] = bv1;
            __syncthreads();
            COMPUTE1();
            __syncthreads();
        }
    }

#pragma unroll
    for (int j = 0; j < 4; ++j) {
        const int n = n0 + wn + j * 16 + l16;
        const float bvl = bias[n];
#pragma unroll
        for (int i = 0; i < 4; ++i) {
            const int mb = m0 + wm + i * 16 + quad * 4;
#pragma unroll
            for (int rg = 0; rg < 4; ++rg) {
                const int m = mb + rg;
                if (m < MTOT) Cf[(size_t)m * DD + n] = acc[i][j][rg] + bvl;
            }
        }
    }
}

// ---------------------------------------------------------------------------
// attn_v4: one block per (b,h); K resident (swizzled), V^T staged from
// global vT by uint4 copies; 5 q-tiles of 64; register softmax; fp16 MFMA.
// ---------------------------------------------------------------------------
__global__ __launch_bounds__(512, 1) void attn_v4(
    const unsigned short* __restrict__ qh, const unsigned short* __restrict__ kh,
    const unsigned short* __restrict__ vT, unsigned short* __restrict__ Xf)
{
    __shared__ unsigned short Ks[288 * 64];
    __shared__ unsigned short Vt[64 * VTS];
    __shared__ unsigned short Qs[64 * 64];
    __shared__ unsigned short Ps[64 * 296];
    __shared__ float sredm[2][64];
    __shared__ float sreds[2][64];

    const int tid = threadIdx.x;
    const int h = blockIdx.x, b = blockIdx.y;
    const int cb = h * HDIM;
    const int lane = tid & 63;
    const int w = tid >> 6;
    const int r0 = (w & 3) * 16;
    const int ch = w >> 2;
    const int l16 = lane & 15;
    const int quad = lane >> 4;

    const size_t kbase = (size_t)(b * SS) * DD + cb;
    {
        const int rr = w * 8 + (lane >> 3);
        const int cg = ((lane & 7) ^ (rr & 7)) * 8;
#pragma unroll
        for (int c = 0; c < 4; ++c)
            gl_lds16(kh + kbase + (size_t)(c * 64 + rr) * DD + cg,
                     &Ks[(c * 64 + w * 8) * 64]);
    }
    if (tid < 256) {
        uint4 z = make_uint4(0, 0, 0, 0);
        if (tid < 8) z = *(const uint4*)&kh[kbase + (size_t)256 * DD + tid * 8];
        *(uint4*)&Ks[256 * 64 + tid * 8] = z;
    }
    // stage V^T rows d=0..63 (uint4 copies; mask pad cols in chunk 32)
    {
        const size_t vbase = (size_t)(b * HH + h) * HDIM * VTS;
        for (int i = tid; i < 64 * 33; i += 512) {
            const int r = i / 33;
            const int c = i - r * 33;
            uint4 v = *(const uint4*)&vT[vbase + (size_t)r * VTS + c * 8];
            if (c == 32) { v.x &= 0xFFFFu; v.y = 0; v.z = 0; v.w = 0; }
            *(uint4*)&Vt[r * VTS + c * 8] = v;
        }
    }

#pragma unroll 1
    for (int qt = 0; qt < 5; ++qt) {
        const int s0 = qt * 64;
        __syncthreads();
        {
            int sg = s0 + (tid >> 3);
            if (sg > SS - 1) sg = SS - 1;
            const int cg = ((tid & 7) ^ ((tid >> 3) & 7)) * 8;
            gl_lds16(qh + (size_t)(b * SS + sg) * DD + cb + cg,
                     &Qs[(w * 8) * 64]);
        }
        __syncthreads();

        f32x4 lac[9];
#pragma unroll
        for (int ct = 0; ct < 9; ++ct) lac[ct] = (f32x4){0.f, 0.f, 0.f, 0.f};
#pragma unroll
        for (int kc = 0; kc < 2; ++kc) {
            const int sb = ((kc * 4 + quad) ^ (l16 & 7)) * 8;
            f16x8 af = *(const f16x8*)&Qs[(r0 + l16) * 64 + sb];
#pragma unroll
            for (int ct = 0; ct < 9; ++ct) {
                const int c0 = ch * 144 + ct * 16;
                f16x8 bf = *(const f16x8*)&Ks[(c0 + l16) * 64 + sb];
                lac[ct] = __builtin_amdgcn_mfma_f32_16x16x32_f16(
                    af, bf, lac[ct], 0, 0, 0);
            }
        }
#pragma unroll
        for (int ct = 0; ct < 9; ++ct) {
            const int t = ch * 144 + ct * 16 + l16;
            if (t > SS - 1) {
                lac[ct][0] = -1e30f; lac[ct][1] = -1e30f;
                lac[ct][2] = -1e30f; lac[ct][3] = -1e30f;
            }
        }
        float mx[4] = {-1e30f, -1e30f, -1e30f, -1e30f};
#pragma unroll
        for (int ct = 0; ct < 9; ++ct)
#pragma unroll
            for (int i = 0; i < 4; ++i) mx[i] = fmaxf(mx[i], lac[ct][i]);
#pragma unroll
        for (int o = 1; o < 16; o <<= 1)
#pragma unroll
            for (int i = 0; i < 4; ++i)
                mx[i] = fmaxf(mx[i], __shfl_xor(mx[i], o, 16));
        if (l16 == 0)
#pragma unroll
            for (int i = 0; i < 4; ++i) sredm[ch][r0 + quad * 4 + i] = mx[i];
        __syncthreads();
#pragma unroll
        for (int i = 0; i < 4; ++i)
            mx[i] = fmaxf(mx[i], sredm[1 - ch][r0 + quad * 4 + i]);
        float sm[4] = {0.f, 0.f, 0.f, 0.f};
#pragma unroll
        for (int ct = 0; ct < 9; ++ct)
#pragma unroll
            for (int i = 0; i < 4; ++i) {
                float pv = __expf(lac[ct][i] - mx[i]);
                lac[ct][i] = pv;
                sm[i] += pv;
            }
#pragma unroll
        for (int o = 1; o < 16; o <<= 1)
#pragma unroll
            for (int i = 0; i < 4; ++i) sm[i] += __shfl_xor(sm[i], o, 16);
        if (l16 == 0)
#pragma unroll
            for (int i = 0; i < 4; ++i) sreds[ch][r0 + quad * 4 + i] = sm[i];
        __syncthreads();
        float inv[4];
#pragma unroll
        for (int i = 0; i < 4; ++i)
            inv[i] = 1.f / (sm[i] + sreds[1 - ch][r0 + quad * 4 + i]);
#pragma unroll
        for (int ct = 0; ct < 9; ++ct) {
            const int col = ch * 144 + ct * 16 + l16;
#pragma unroll
            for (int i = 0; i < 4; ++i)
                Ps[(r0 + quad * 4 + i) * 296 + col] =
                    f16b(lac[ct][i] * inv[i]);
        }
        __syncthreads();

        f32x4 oacc[2];
        oacc[0] = (f32x4){0.f, 0.f, 0.f, 0.f};
        oacc[1] = (f32x4){0.f, 0.f, 0.f, 0.f};
#pragma unroll
        for (int tt = 0; tt < 9; ++tt) {
            const int t0 = tt * 32;
            f16x8 pf = *(const f16x8*)&Ps[(r0 + l16) * 296 + t0 + quad * 8];
#pragma unroll
            for (int dt = 0; dt < 2; ++dt) {
                f16x8 bvv = *(const f16x8*)&Vt[(ch * 32 + dt * 16 + l16) * VTS +
                                               t0 + quad * 8];
                oacc[dt] = __builtin_amdgcn_mfma_f32_16x16x32_f16(
                    pf, bvv, oacc[dt], 0, 0, 0);
            }
        }
#pragma unroll
        for (int dt = 0; dt < 2; ++dt)
#pragma unroll
            for (int i = 0; i < 4; ++i) {
                const int srow = s0 + r0 + quad * 4 + i;
                if (srow < SS)
                    Xf[(size_t)(b * SS + srow) * DD + cb + ch * 32 + dt * 16 +
                       l16] = f16b(oacc[dt][i]);
            }
    }
}

// ---------------------------------------------------------------------------
extern "C" void kernel_launch(void* const* d_in, const int* in_sizes, int n_in,
                              void* d_out, int out_size, void* d_ws,
                              size_t ws_size, hipStream_t stream)
{
    const float* hidden = (const float*)d_in[0];
    const int* tki = (const int*)d_in[1];
    const float* tkg = (const float*)d_in[2];
    const float* wq = (const float*)d_in[3];
    const float* Aq = (const float*)d_in[4];
    const float* Bq = (const float*)d_in[5];
    const float* bq = (const float*)d_in[6];
    const float* wk = (const float*)d_in[7];
    const float* Ak = (const float*)d_in[8];
    const float* Bk = (const float*)d_in[9];
    const float* bkb = (const float*)d_in[10];
    const float* wv = (const float*)d_in[11];
    const float* Av = (const float*)d_in[12];
    const float* Bv = (const float*)d_in[13];
    const float* bvb = (const float*)d_in[14];
    const float* wo = (const float*)d_in[15];
    const float* Ao = (const float*)d_in[16];
    const float* Bo = (const float*)d_in[17];
    const float* bob = (const float*)d_in[18];
    float* out = (float*)d_out;

    // ---- workspace (~71 MB) ----
    char* ws = (char*)d_ws;
    const size_t NW = (size_t)DD * DD;
    const size_t NA = (size_t)EE * RR * DD;
    unsigned short* Xf = (unsigned short*)ws;    ws += (size_t)MPAD * DD * 2;
    unsigned short* qh = (unsigned short*)ws;    ws += (size_t)MTOT * DD * 2;
    unsigned short* vTg = (unsigned short*)ws;   ws += (size_t)BB * HH * HDIM * VTS * 2;
    unsigned short* Wcat = (unsigned short*)ws;  ws += 3 * NW * 2;
    unsigned short* Who = (unsigned short*)ws;   ws += NW * 2;
    unsigned short* A3 = (unsigned short*)ws;    ws += 3 * NA * 2;
    unsigned short* Ao16 = (unsigned short*)ws;  ws += NA * 2;
    unsigned short* Bccat = (unsigned short*)ws; ws += (size_t)BB * 3072 * 32 * 2;
    unsigned short* Bco = (unsigned short*)ws;   ws += (size_t)BB * 1024 * 32 * 2;
    unsigned short* XAo = (unsigned short*)ws;   ws += (size_t)MTOT * 128 * 2;
    // parked in d_out (dead before gemm_o writes out):
    unsigned short* kh = (unsigned short*)d_out;
    unsigned short* XAd = (unsigned short*)((char*)d_out + (size_t)MTOT * DD * 2);

    prep<<<13952, 256, 0, stream>>>(hidden, wq, wk, wv, wo, Aq, Ak, Av, Ao,
                                    Bq, Bk, Bv, Bo, tki, tkg, Xf, Wcat, Who,
                                    A3, Ao16, Bccat, Bco);
    gemm_xa<<<dim3(3, 65), 256, 0, stream>>>(Xf, A3, A3 + NA, A3 + 2 * NA,
                                             XAd, 384);
    gemm_qkv<<<dim3(24, 65), 256, 0, stream>>>(Xf, Wcat, bq, bkb, bvb, XAd,
                                               Bccat, tki, qh, kh, vTg);
    attn_v4<<<dim3(HH, BB), 512, 0, stream>>>(qh, kh, vTg, Xf);
    gemm_xa<<<dim3(1, 65), 256, 0, stream>>>(Xf, Ao16, Ao16, Ao16, XAo, 128);
    gemm_o<<<dim3(8, 65), 256, 0, stream>>>(Xf, Who, bob, XAo, Bco, tki, out);
}